// Round 2
// baseline (2092.313 us; speedup 1.0000x reference)
//
#include <hip/hip_runtime.h>
#include <hip/hip_bf16.h>

typedef __bf16 bf16x8 __attribute__((ext_vector_type(8)));
typedef float f32x4 __attribute__((ext_vector_type(4)));
typedef unsigned int u32x4 __attribute__((ext_vector_type(4)));

using bf16 = __hip_bfloat16;

// ---------------- elementwise fp32 -> bf16 ----------------
__global__ __launch_bounds__(256) void k_cvt_bf16(const float* __restrict__ in,
                                                  bf16* __restrict__ out) {
  const int i = (blockIdx.x * 256 + threadIdx.x) * 4;
  float4 v = *reinterpret_cast<const float4*>(in + i);
  out[i + 0] = __float2bfloat16(v.x);
  out[i + 1] = __float2bfloat16(v.y);
  out[i + 2] = __float2bfloat16(v.z);
  out[i + 3] = __float2bfloat16(v.w);
}

// ---------------- weight transpose + convert: wt[n][k] = (bf16)w[k][n] ----------------
__global__ __launch_bounds__(256) void k_transpose_bf16(const float* __restrict__ w,
                                                        bf16* __restrict__ wt,
                                                        int K, int N) {
  __shared__ float t[32][33];
  const int k0 = blockIdx.x * 32, n0 = blockIdx.y * 32;
  const int tx = threadIdx.x & 31, ty = threadIdx.x >> 5;
#pragma unroll
  for (int i = 0; i < 32; i += 8)
    t[ty + i][tx] = w[(size_t)(k0 + ty + i) * N + n0 + tx];
  __syncthreads();
#pragma unroll
  for (int i = 0; i < 32; i += 8)
    wt[(size_t)(n0 + ty + i) * K + k0 + tx] = __float2bfloat16(t[tx][ty + i]);
}

// ---------------- GEMM: C[M,N] = A[M,K] * Bt[N,K]^T  (bf16 in, fp32 acc) ----------------
// A may be split along K into up to 4 sources (each [M, srcK]), switching every
// split_bk K-steps (BK=64).  Output: bf16 (Cb) or fp32+bias (Cf).
__global__ __launch_bounds__(256) void k_gemm_bt(
    const bf16* __restrict__ A0, const bf16* __restrict__ A1,
    const bf16* __restrict__ A2, const bf16* __restrict__ A3,
    const bf16* __restrict__ Bt, bf16* __restrict__ Cb,
    float* __restrict__ Cf, const float* __restrict__ bias,
    int N, int K, int srcK, int split_bk) {
  __shared__ __align__(16) bf16 As[128 * 64];
  __shared__ __align__(16) bf16 Bs[128 * 64];
  const int tid = threadIdx.x;
  const int lane = tid & 63;
  const int wv = tid >> 6;
  const size_t M0 = (size_t)blockIdx.x * 128;
  const int N0 = blockIdx.y * 128;
  const int wr = (wv >> 1) * 64, wc = (wv & 1) * 64;
  const int fr = lane & 15, fo = (lane >> 4) * 8;
  const int crow = tid >> 3, ckc = (tid & 7) << 3;
  f32x4 acc[4][4] = {};

  const int nsteps = K >> 6;
  for (int kt = 0; kt < nsteps; ++kt) {
    const int s = kt / split_bk;
    const bf16* __restrict__ Ak = (s == 0) ? A0 : (s == 1) ? A1 : (s == 2) ? A2 : A3;
    const size_t aofs = (size_t)(kt - s * split_bk) * 64;
    const size_t bofs = (size_t)kt * 64;
    __syncthreads();
#pragma unroll
    for (int i = 0; i < 4; ++i) {
      const int row = i * 32 + crow;
      u32x4 av = *reinterpret_cast<const u32x4*>(Ak + (M0 + row) * (size_t)srcK + aofs + ckc);
      u32x4 bv = *reinterpret_cast<const u32x4*>(Bt + (size_t)(N0 + row) * K + bofs + ckc);
      *reinterpret_cast<u32x4*>(As + row * 64 + ckc) = av;
      *reinterpret_cast<u32x4*>(Bs + row * 64 + ckc) = bv;
    }
    __syncthreads();
#pragma unroll
    for (int kk = 0; kk < 64; kk += 32) {
      bf16x8 a[4], b[4];
#pragma unroll
      for (int m = 0; m < 4; ++m)
        a[m] = *reinterpret_cast<const bf16x8*>(As + (wr + m * 16 + fr) * 64 + kk + fo);
#pragma unroll
      for (int n = 0; n < 4; ++n)
        b[n] = *reinterpret_cast<const bf16x8*>(Bs + (wc + n * 16 + fr) * 64 + kk + fo);
#pragma unroll
      for (int m = 0; m < 4; ++m)
#pragma unroll
        for (int n = 0; n < 4; ++n)
          acc[m][n] = __builtin_amdgcn_mfma_f32_16x16x32_bf16(a[m], b[n], acc[m][n], 0, 0, 0);
    }
  }

  const int rb = (lane >> 4) * 4;
#pragma unroll
  for (int m = 0; m < 4; ++m) {
#pragma unroll
    for (int n = 0; n < 4; ++n) {
      const size_t row = M0 + wr + m * 16 + rb;
      const int col = N0 + wc + n * 16 + fr;
      if (Cb != nullptr) {
#pragma unroll
        for (int r = 0; r < 4; ++r)
          Cb[(row + r) * N + col] = __float2bfloat16(acc[m][n][r]);
      } else {
        const float bb = bias[col];
#pragma unroll
        for (int r = 0; r < 4; ++r)
          Cf[(row + r) * N + col] = acc[m][n][r] + bb;
      }
    }
  }
}

// ---------------- depthwise conv (KSxKS, SAME) on [B,4096,768] token-major ----------------
template <int KS>
__global__ __launch_bounds__(256) void k_dwconv(const bf16* __restrict__ in,
                                                const float* __restrict__ w,
                                                bf16* __restrict__ out) {
  const int idx = blockIdx.x * 256 + threadIdx.x;
  const int c = idx % 768;
  const int t = idx / 768;
  const int n = t & 4095;
  const int b = t >> 12;
  const int y = n >> 6, x = n & 63;
  constexpr int P = KS / 2;
  const float* __restrict__ wc = w + c * KS * KS;
  const bf16* __restrict__ ip = in + (size_t)b * 4096 * 768 + c;
  float acc = 0.f;
#pragma unroll
  for (int ky = 0; ky < KS; ++ky) {
    const int yy = y + ky - P;
    if (yy < 0 || yy > 63) continue;
#pragma unroll
    for (int kx = 0; kx < KS; ++kx) {
      const int xx = x + kx - P;
      if (xx < 0 || xx > 63) continue;
      acc += __bfloat162float(ip[(size_t)(yy * 64 + xx) * 768]) * wc[ky * KS + kx];
    }
  }
  out[idx] = __float2bfloat16(acc);
}

// ---------------- grouped 1x1 conv: 24 groups of 32->32 ----------------
__global__ __launch_bounds__(256) void k_pwconv(const bf16* __restrict__ in,
                                                const float* __restrict__ w,
                                                bf16* __restrict__ out) {
  const int idx = blockIdx.x * 256 + threadIdx.x;
  const int co = idx % 768;
  const int tok = idx / 768;  // b*4096 + n
  const int g = co >> 5;
  const bf16* __restrict__ ip = in + (size_t)tok * 768 + g * 32;
  const float* __restrict__ wp = w + co * 32;
  float acc = 0.f;
#pragma unroll
  for (int ci = 0; ci < 32; ++ci)
    acc += __bfloat162float(ip[ci]) * wp[ci];
  out[idx] = __float2bfloat16(acc);
}

// ---------------- chunked flash attention ----------------
// msq [B,4096,768] = [q(0:256) | k(256:512) | v(512:768)], per head h: cols h*32..+32
// grid: x = q-tile (64 rows) in chunk (32), y = combo b*16 + h*2 + chunk (32)
__global__ __launch_bounds__(256) void k_attn(const bf16* __restrict__ msq,
                                              bf16* __restrict__ out) {
  const int qt = blockIdx.x;
  const int combo = blockIdx.y;
  const int b = combo >> 4;
  const int h = (combo >> 1) & 7;
  const int ck = combo & 1;
  const int tid = threadIdx.x, lane = tid & 63, wv = tid >> 6;
  const int fr = lane & 15, fo = (lane >> 4) * 8;
  const size_t base = (size_t)b * 4096 * 768;
  const int n0 = ck * 2048 + qt * 64;

  __shared__ __align__(16) bf16 Kl[64][40];      // K tile [kv][hd], padded
  __shared__ __align__(16) bf16 Vt[32][72];      // V tile transposed [hd][kv], padded
  __shared__ __align__(16) bf16 Pl[4][16][72];   // per-wave P round-trip

  const int qrow = n0 + wv * 16 + fr;
  const bf16x8 qf = *reinterpret_cast<const bf16x8*>(msq + base + (size_t)qrow * 768 + h * 32 + fo);

  const float scale = 0.17677669529663687f;  // 1/sqrt(32)
  f32x4 oacc[2] = {};
  float mrun[4] = {-1e30f, -1e30f, -1e30f, -1e30f};
  float lrun[4] = {0.f, 0.f, 0.f, 0.f};
  const int sr = tid >> 2, sdc = (tid & 3) << 3;

  for (int kt = 0; kt < 32; ++kt) {
    const int m0 = ck * 2048 + kt * 64;
    __syncthreads();
    {
      const size_t rbase = base + (size_t)(m0 + sr) * 768 + h * 32;
      u32x4 kv = *reinterpret_cast<const u32x4*>(msq + rbase + 256 + sdc);
      *reinterpret_cast<u32x4*>(&Kl[sr][sdc]) = kv;
      u32x4 vvv = *reinterpret_cast<const u32x4*>(msq + rbase + 512 + sdc);
      const bf16* vp = reinterpret_cast<const bf16*>(&vvv);
#pragma unroll
      for (int j = 0; j < 8; ++j) Vt[sdc + j][sr] = vp[j];
    }
    __syncthreads();

    // S = Q K^T  (16 q-rows x 64 kv-cols per wave)
    f32x4 sacc[4];
#pragma unroll
    for (int j = 0; j < 4; ++j) {
      const bf16x8 kfb = *reinterpret_cast<const bf16x8*>(&Kl[j * 16 + fr][fo]);
      f32x4 z = {0.f, 0.f, 0.f, 0.f};
      sacc[j] = __builtin_amdgcn_mfma_f32_16x16x32_bf16(qf, kfb, z, 0, 0, 0);
    }

    // online softmax (row r lives in 16 lanes sharing lane>>4)
    float sv[4][4];
    float corr[4];
#pragma unroll
    for (int r = 0; r < 4; ++r) {
      float mx = -1e30f;
#pragma unroll
      for (int j = 0; j < 4; ++j) {
        const float s = sacc[j][r] * scale;
        sv[j][r] = s;
        mx = fmaxf(mx, s);
      }
#pragma unroll
      for (int off = 8; off >= 1; off >>= 1) mx = fmaxf(mx, __shfl_xor(mx, off));
      const float mnew = fmaxf(mrun[r], mx);
      corr[r] = __expf(mrun[r] - mnew);
      mrun[r] = mnew;
      float sm = 0.f;
#pragma unroll
      for (int j = 0; j < 4; ++j) {
        const float pz = __expf(sv[j][r] - mnew);
        sv[j][r] = pz;
        sm += pz;
      }
#pragma unroll
      for (int off = 8; off >= 1; off >>= 1) sm += __shfl_xor(sm, off);
      lrun[r] = lrun[r] * corr[r] + sm;
    }

    // P -> per-wave LDS (D-layout) and O rescale
    const int prow = (lane >> 4) * 4;
#pragma unroll
    for (int r = 0; r < 4; ++r)
#pragma unroll
      for (int j = 0; j < 4; ++j)
        Pl[wv][prow + r][j * 16 + fr] = __float2bfloat16(sv[j][r]);
#pragma unroll
    for (int nb = 0; nb < 2; ++nb)
#pragma unroll
      for (int r = 0; r < 4; ++r) oacc[nb][r] *= corr[r];

    // O += P @ V
#pragma unroll
    for (int kk = 0; kk < 2; ++kk) {
      const bf16x8 pa = *reinterpret_cast<const bf16x8*>(&Pl[wv][fr][kk * 32 + fo]);
#pragma unroll
      for (int nb = 0; nb < 2; ++nb) {
        const bf16x8 vb = *reinterpret_cast<const bf16x8*>(&Vt[nb * 16 + fr][kk * 32 + fo]);
        oacc[nb] = __builtin_amdgcn_mfma_f32_16x16x32_bf16(pa, vb, oacc[nb], 0, 0, 0);
      }
    }
  }

  const int rb = (lane >> 4) * 4;
#pragma unroll
  for (int nb = 0; nb < 2; ++nb)
#pragma unroll
    for (int r = 0; r < 4; ++r) {
      const int row = n0 + wv * 16 + rb + r;
      out[((size_t)b * 4096 + row) * 256 + h * 32 + nb * 16 + fr] =
          __float2bfloat16(oacc[nb][r] / lrun[r]);
    }
}

// ---------------- launcher ----------------
extern "C" void kernel_launch(void* const* d_in, const int* in_sizes, int n_in,
                              void* d_out, int out_size, void* d_ws, size_t ws_size,
                              hipStream_t stream) {
  (void)in_sizes; (void)n_in; (void)out_size; (void)ws_size;
  const float* x    = (const float*)d_in[0];
  const float* wrd  = (const float*)d_in[1];
  const float* wqkv = (const float*)d_in[2];
  const float* dw0  = (const float*)d_in[3];
  const float* pw0  = (const float*)d_in[4];
  const float* dw1  = (const float*)d_in[5];
  const float* pw1  = (const float*)d_in[6];
  const float* dw2  = (const float*)d_in[7];
  const float* pw2  = (const float*)d_in[8];
  const float* wrd2 = (const float*)d_in[9];
  const float* wprj = (const float*)d_in[10];
  const float* bprj = (const float*)d_in[11];
  float* out = (float*)d_out;

  char* p = (char*)d_ws;
  auto nxt = [&](size_t bytes) {
    char* r = p;
    p += (bytes + 255) & ~(size_t)255;
    return (bf16*)r;
  };
  bf16* xb   = nxt(8192ull * 512 * 2);
  bf16* wrT  = nxt(256ull * 512 * 2);
  bf16* wqT  = nxt(768ull * 256 * 2);
  bf16* wr2T = nxt(768ull * 3072 * 2);
  bf16* wpT  = nxt(512ull * 256 * 2);
  bf16* xr   = nxt(8192ull * 256 * 2);
  bf16* qkv  = nxt(8192ull * 768 * 2);
  bf16* tmp  = nxt(8192ull * 768 * 2);
  bf16* y0   = nxt(8192ull * 768 * 2);
  bf16* y1   = nxt(8192ull * 768 * 2);
  bf16* y2   = nxt(8192ull * 768 * 2);
  bf16* msq  = nxt(8192ull * 768 * 2);
  bf16* ao   = nxt(8192ull * 256 * 2);

  // prep: convert activations + transpose weights to bf16 B^T
  k_cvt_bf16<<<(8192 * 512 / 4) / 256, 256, 0, stream>>>(x, xb);
  k_transpose_bf16<<<dim3(512 / 32, 256 / 32), 256, 0, stream>>>(wrd, wrT, 512, 256);
  k_transpose_bf16<<<dim3(256 / 32, 768 / 32), 256, 0, stream>>>(wqkv, wqT, 256, 768);
  k_transpose_bf16<<<dim3(3072 / 32, 768 / 32), 256, 0, stream>>>(wrd2, wr2T, 3072, 768);
  k_transpose_bf16<<<dim3(256 / 32, 512 / 32), 256, 0, stream>>>(wprj, wpT, 256, 512);

  // GEMM1: xr = x @ w_reduce   (M=8192 N=256 K=512)
  k_gemm_bt<<<dim3(64, 2), 256, 0, stream>>>(xb, xb, xb, xb, wrT, xr, nullptr, nullptr,
                                             256, 512, 512, 1 << 20);
  // GEMM2: qkv = xr @ w_qkv    (N=768 K=256)
  k_gemm_bt<<<dim3(64, 6), 256, 0, stream>>>(xr, xr, xr, xr, wqT, qkv, nullptr, nullptr,
                                             768, 256, 256, 1 << 20);

  // conv branches (dw then grouped pw), token-major layout
  k_dwconv<3><<<24576, 256, 0, stream>>>(qkv, dw0, tmp);
  k_pwconv<<<24576, 256, 0, stream>>>(tmp, pw0, y0);
  k_dwconv<5><<<24576, 256, 0, stream>>>(qkv, dw1, tmp);
  k_pwconv<<<24576, 256, 0, stream>>>(tmp, pw1, y1);
  k_dwconv<7><<<24576, 256, 0, stream>>>(qkv, dw2, tmp);
  k_pwconv<<<24576, 256, 0, stream>>>(tmp, pw2, y2);

  // GEMM3: msq = [qkv|y0|y1|y2] @ w_reduce2  (N=768 K=3072, 4 sources of 768)
  k_gemm_bt<<<dim3(64, 6), 256, 0, stream>>>(qkv, y0, y1, y2, wr2T, msq, nullptr, nullptr,
                                             768, 3072, 768, 12);

  // chunked attention
  k_attn<<<dim3(32, 32), 256, 0, stream>>>(msq, ao);

  // GEMM4: out = ao @ w_proj + b_proj (fp32 out)
  k_gemm_bt<<<dim3(64, 4), 256, 0, stream>>>(ao, ao, ao, ao, wpT, nullptr, out, bprj,
                                             512, 256, 256, 1 << 20);
}

// Round 3
// 449.085 us; speedup vs baseline: 4.6591x; 4.6591x over previous
//
#include <hip/hip_runtime.h>
#include <hip/hip_bf16.h>

typedef __bf16 bf16x8 __attribute__((ext_vector_type(8)));
typedef float f32x4 __attribute__((ext_vector_type(4)));
typedef unsigned int u32x4 __attribute__((ext_vector_type(4)));

using bf16 = __hip_bfloat16;

// ---------------- elementwise fp32 -> bf16 ----------------
__global__ __launch_bounds__(256) void k_cvt_bf16(const float* __restrict__ in,
                                                  bf16* __restrict__ out) {
  const int i = (blockIdx.x * 256 + threadIdx.x) * 4;
  float4 v = *reinterpret_cast<const float4*>(in + i);
  out[i + 0] = __float2bfloat16(v.x);
  out[i + 1] = __float2bfloat16(v.y);
  out[i + 2] = __float2bfloat16(v.z);
  out[i + 3] = __float2bfloat16(v.w);
}

// ---------------- weight transpose + convert: wt[n][k] = (bf16)w[k][n] ----------------
__global__ __launch_bounds__(256) void k_transpose_bf16(const float* __restrict__ w,
                                                        bf16* __restrict__ wt,
                                                        int K, int N) {
  __shared__ float t[32][33];
  const int k0 = blockIdx.x * 32, n0 = blockIdx.y * 32;
  const int tx = threadIdx.x & 31, ty = threadIdx.x >> 5;
#pragma unroll
  for (int i = 0; i < 32; i += 8)
    t[ty + i][tx] = w[(size_t)(k0 + ty + i) * N + n0 + tx];
  __syncthreads();
#pragma unroll
  for (int i = 0; i < 32; i += 8)
    wt[(size_t)(n0 + ty + i) * K + k0 + tx] = __float2bfloat16(t[tx][ty + i]);
}

// ---------------- bf16 2D transpose per batch: in [z][R][C] -> out [z][C][R] ----------------
__global__ __launch_bounds__(256) void k_transpose2d(const bf16* __restrict__ in,
                                                     bf16* __restrict__ out,
                                                     int R, int C) {
  __shared__ unsigned short tl[64][65];
  const int c0 = blockIdx.x * 64, r0 = blockIdx.y * 64;
  const size_t zb = (size_t)blockIdx.z * R * C;
  const int tx = threadIdx.x & 63, ty = threadIdx.x >> 6;
  const unsigned short* ip = (const unsigned short*)in + zb;
  unsigned short* op = (unsigned short*)out + zb;
#pragma unroll
  for (int i = 0; i < 64; i += 4)
    tl[ty + i][tx] = ip[(size_t)(r0 + ty + i) * C + c0 + tx];
  __syncthreads();
#pragma unroll
  for (int i = 0; i < 64; i += 4)
    op[(size_t)(c0 + ty + i) * R + r0 + tx] = tl[tx][ty + i];
}

// ---------------- GEMM: C[M,N] = A[M,K] * Bt[N,K]^T  (bf16 in, fp32 acc) ----------------
__global__ __launch_bounds__(256) void k_gemm_bt(
    const bf16* __restrict__ A0, const bf16* __restrict__ A1,
    const bf16* __restrict__ A2, const bf16* __restrict__ A3,
    const bf16* __restrict__ Bt, bf16* __restrict__ Cb,
    float* __restrict__ Cf, const float* __restrict__ bias,
    int N, int K, int srcK, int split_bk) {
  __shared__ __align__(16) bf16 As[128 * 64];
  __shared__ __align__(16) bf16 Bs[128 * 64];
  const int tid = threadIdx.x;
  const int lane = tid & 63;
  const int wv = tid >> 6;
  const size_t M0 = (size_t)blockIdx.x * 128;
  const int N0 = blockIdx.y * 128;
  const int wr = (wv >> 1) * 64, wc = (wv & 1) * 64;
  const int fr = lane & 15, fo = (lane >> 4) * 8;
  const int crow = tid >> 3, ckc = (tid & 7) << 3;
  f32x4 acc[4][4] = {};

  const int nsteps = K >> 6;
  for (int kt = 0; kt < nsteps; ++kt) {
    const int s = kt / split_bk;
    const bf16* __restrict__ Ak = (s == 0) ? A0 : (s == 1) ? A1 : (s == 2) ? A2 : A3;
    const size_t aofs = (size_t)(kt - s * split_bk) * 64;
    const size_t bofs = (size_t)kt * 64;
    __syncthreads();
#pragma unroll
    for (int i = 0; i < 4; ++i) {
      const int row = i * 32 + crow;
      u32x4 av = *reinterpret_cast<const u32x4*>(Ak + (M0 + row) * (size_t)srcK + aofs + ckc);
      u32x4 bv = *reinterpret_cast<const u32x4*>(Bt + (size_t)(N0 + row) * K + bofs + ckc);
      *reinterpret_cast<u32x4*>(As + row * 64 + ckc) = av;
      *reinterpret_cast<u32x4*>(Bs + row * 64 + ckc) = bv;
    }
    __syncthreads();
#pragma unroll
    for (int kk = 0; kk < 64; kk += 32) {
      bf16x8 a[4], b[4];
#pragma unroll
      for (int m = 0; m < 4; ++m)
        a[m] = *reinterpret_cast<const bf16x8*>(As + (wr + m * 16 + fr) * 64 + kk + fo);
#pragma unroll
      for (int n = 0; n < 4; ++n)
        b[n] = *reinterpret_cast<const bf16x8*>(Bs + (wc + n * 16 + fr) * 64 + kk + fo);
#pragma unroll
      for (int m = 0; m < 4; ++m)
#pragma unroll
        for (int n = 0; n < 4; ++n)
          acc[m][n] = __builtin_amdgcn_mfma_f32_16x16x32_bf16(a[m], b[n], acc[m][n], 0, 0, 0);
    }
  }

  const int rb = (lane >> 4) * 4;
#pragma unroll
  for (int m = 0; m < 4; ++m) {
#pragma unroll
    for (int n = 0; n < 4; ++n) {
      const size_t row = M0 + wr + m * 16 + rb;
      const int col = N0 + wc + n * 16 + fr;
      if (Cb != nullptr) {
#pragma unroll
        for (int r = 0; r < 4; ++r)
          Cb[(row + r) * N + col] = __float2bfloat16(acc[m][n][r]);
      } else {
        const float bb = bias[col];
#pragma unroll
        for (int r = 0; r < 4; ++r)
          Cf[(row + r) * N + col] = acc[m][n][r] + bb;
      }
    }
  }
}

// ---------------- depthwise conv, NCHW planes, LDS-staged ----------------
// in/out: [2][768][4096] (plane-major). One block per (c, b) plane.
template <int KS>
__global__ __launch_bounds__(256) void k_dwconv_img(const bf16* __restrict__ in,
                                                    const float* __restrict__ w,
                                                    bf16* __restrict__ out) {
  constexpr int P = KS / 2;
  constexpr int ROWS = 64 + 2 * P;
  constexpr int PITCH = 80;  // bf16 elems; 160B rows keep 16B-aligned staging
  constexpr int NCHUNK = ROWS * PITCH * 2 / 16;
  __shared__ __align__(16) bf16 pl[ROWS * PITCH];
  const int t = threadIdx.x;
  const int c = blockIdx.x, b = blockIdx.y;
  const bf16* __restrict__ ip = in + ((size_t)b * 768 + c) * 4096;
  bf16* __restrict__ op = out + ((size_t)b * 768 + c) * 4096;

  // zero LDS (halo must be 0 for SAME padding)
  u32x4* pl4 = reinterpret_cast<u32x4*>(pl);
  for (int i = t; i < NCHUNK; i += 256) pl4[i] = u32x4{0, 0, 0, 0};
  __syncthreads();
  // stage plane: interior at col offset 8 (16B aligned)
  for (int q = t; q < 512; q += 256) {
    const int px0 = q * 8;
    const int y = px0 >> 6, x = px0 & 63;
    u32x4 v = *reinterpret_cast<const u32x4*>(ip + px0);
    *reinterpret_cast<u32x4*>(&pl[(y + P) * PITCH + 8 + x]) = v;
  }
  __syncthreads();

  // weights: uniform per block -> scalar loads
  float wk[KS * KS];
#pragma unroll
  for (int i = 0; i < KS * KS; ++i) wk[i] = w[c * KS * KS + i];

  const int x = t & 63;        // lanes read consecutive bf16 -> conflict-free
  const int y0 = (t >> 6) * 16;
  float win[KS][KS];
#pragma unroll
  for (int r = 0; r < 2 * P; ++r)
#pragma unroll
    for (int kx = 0; kx < KS; ++kx)
      win[r % KS][kx] = __bfloat162float(pl[(y0 + r) * PITCH + 8 + x - P + kx]);
#pragma unroll
  for (int yy = 0; yy < 16; ++yy) {
    constexpr int twoP = 2 * P;
#pragma unroll
    for (int kx = 0; kx < KS; ++kx)
      win[(yy + twoP) % KS][kx] =
          __bfloat162float(pl[(y0 + yy + twoP) * PITCH + 8 + x - P + kx]);
    float acc = 0.f;
#pragma unroll
    for (int ky = 0; ky < KS; ++ky)
#pragma unroll
      for (int kx = 0; kx < KS; ++kx)
        acc += win[(yy + ky) % KS][kx] * wk[ky * KS + kx];
    op[(y0 + yy) * 64 + x] = __float2bfloat16(acc);
  }
}

// ---------------- grouped 1x1 conv, NCHW planes ----------------
// grid: (192 co-quads, 2 px-halves, 2 b); thread: 4 co x 8 px
__global__ __launch_bounds__(256) void k_pwconv_img(const bf16* __restrict__ in,
                                                    const float* __restrict__ w,
                                                    bf16* __restrict__ out) {
  const int co0 = blockIdx.x * 4;
  const int g = co0 >> 5;
  const int b = blockIdx.z;
  const int px = blockIdx.y * 2048 + threadIdx.x * 8;
  const bf16* __restrict__ ip = in + ((size_t)b * 768 + g * 32) * 4096 + px;
  float acc[4][8] = {};
#pragma unroll
  for (int ci = 0; ci < 32; ++ci) {
    const bf16x8 v = *reinterpret_cast<const bf16x8*>(ip + (size_t)ci * 4096);
    float fv[8];
#pragma unroll
    for (int j = 0; j < 8; ++j) fv[j] = (float)v[j];
#pragma unroll
    for (int q = 0; q < 4; ++q) {
      const float wq = w[(co0 + q) * 32 + ci];
#pragma unroll
      for (int j = 0; j < 8; ++j) acc[q][j] += wq * fv[j];
    }
  }
#pragma unroll
  for (int q = 0; q < 4; ++q) {
    bf16x8 o;
#pragma unroll
    for (int j = 0; j < 8; ++j) o[j] = (__bf16)acc[q][j];
    *reinterpret_cast<bf16x8*>(out + ((size_t)b * 768 + co0 + q) * 4096 + px) = o;
  }
}

// ---------------- chunked flash attention ----------------
__global__ __launch_bounds__(256) void k_attn(const bf16* __restrict__ msq,
                                              bf16* __restrict__ out) {
  const int qt = blockIdx.x;
  const int combo = blockIdx.y;
  const int b = combo >> 4;
  const int h = (combo >> 1) & 7;
  const int ck = combo & 1;
  const int tid = threadIdx.x, lane = tid & 63, wv = tid >> 6;
  const int fr = lane & 15, fo = (lane >> 4) * 8;
  const size_t base = (size_t)b * 4096 * 768;
  const int n0 = ck * 2048 + qt * 64;

  __shared__ __align__(16) bf16 Kl[64][40];
  __shared__ __align__(16) bf16 Vt[32][72];
  __shared__ __align__(16) bf16 Pl[4][16][72];

  const int qrow = n0 + wv * 16 + fr;
  const bf16x8 qf = *reinterpret_cast<const bf16x8*>(msq + base + (size_t)qrow * 768 + h * 32 + fo);

  const float scale = 0.17677669529663687f;
  f32x4 oacc[2] = {};
  float mrun[4] = {-1e30f, -1e30f, -1e30f, -1e30f};
  float lrun[4] = {0.f, 0.f, 0.f, 0.f};
  const int sr = tid >> 2, sdc = (tid & 3) << 3;

  for (int kt = 0; kt < 32; ++kt) {
    const int m0 = ck * 2048 + kt * 64;
    __syncthreads();
    {
      const size_t rbase = base + (size_t)(m0 + sr) * 768 + h * 32;
      u32x4 kv = *reinterpret_cast<const u32x4*>(msq + rbase + 256 + sdc);
      *reinterpret_cast<u32x4*>(&Kl[sr][sdc]) = kv;
      u32x4 vvv = *reinterpret_cast<const u32x4*>(msq + rbase + 512 + sdc);
      const bf16* vp = reinterpret_cast<const bf16*>(&vvv);
#pragma unroll
      for (int j = 0; j < 8; ++j) Vt[sdc + j][sr] = vp[j];
    }
    __syncthreads();

    f32x4 sacc[4];
#pragma unroll
    for (int j = 0; j < 4; ++j) {
      const bf16x8 kfb = *reinterpret_cast<const bf16x8*>(&Kl[j * 16 + fr][fo]);
      f32x4 z = {0.f, 0.f, 0.f, 0.f};
      sacc[j] = __builtin_amdgcn_mfma_f32_16x16x32_bf16(qf, kfb, z, 0, 0, 0);
    }

    float sv[4][4];
    float corr[4];
#pragma unroll
    for (int r = 0; r < 4; ++r) {
      float mx = -1e30f;
#pragma unroll
      for (int j = 0; j < 4; ++j) {
        const float s = sacc[j][r] * scale;
        sv[j][r] = s;
        mx = fmaxf(mx, s);
      }
#pragma unroll
      for (int off = 8; off >= 1; off >>= 1) mx = fmaxf(mx, __shfl_xor(mx, off));
      const float mnew = fmaxf(mrun[r], mx);
      corr[r] = __expf(mrun[r] - mnew);
      mrun[r] = mnew;
      float sm = 0.f;
#pragma unroll
      for (int j = 0; j < 4; ++j) {
        const float pz = __expf(sv[j][r] - mnew);
        sv[j][r] = pz;
        sm += pz;
      }
#pragma unroll
      for (int off = 8; off >= 1; off >>= 1) sm += __shfl_xor(sm, off);
      lrun[r] = lrun[r] * corr[r] + sm;
    }

    const int prow = (lane >> 4) * 4;
#pragma unroll
    for (int r = 0; r < 4; ++r)
#pragma unroll
      for (int j = 0; j < 4; ++j)
        Pl[wv][prow + r][j * 16 + fr] = __float2bfloat16(sv[j][r]);
#pragma unroll
    for (int nb = 0; nb < 2; ++nb)
#pragma unroll
      for (int r = 0; r < 4; ++r) oacc[nb][r] *= corr[r];

#pragma unroll
    for (int kk = 0; kk < 2; ++kk) {
      const bf16x8 pa = *reinterpret_cast<const bf16x8*>(&Pl[wv][fr][kk * 32 + fo]);
#pragma unroll
      for (int nb = 0; nb < 2; ++nb) {
        const bf16x8 vb = *reinterpret_cast<const bf16x8*>(&Vt[nb * 16 + fr][kk * 32 + fo]);
        oacc[nb] = __builtin_amdgcn_mfma_f32_16x16x32_bf16(pa, vb, oacc[nb], 0, 0, 0);
      }
    }
  }

  const int rb = (lane >> 4) * 4;
#pragma unroll
  for (int nb = 0; nb < 2; ++nb)
#pragma unroll
    for (int r = 0; r < 4; ++r) {
      const int row = n0 + wv * 16 + rb + r;
      out[((size_t)b * 4096 + row) * 256 + h * 32 + nb * 16 + fr] =
          __float2bfloat16(oacc[nb][r] / lrun[r]);
    }
}

// ---------------- launcher ----------------
extern "C" void kernel_launch(void* const* d_in, const int* in_sizes, int n_in,
                              void* d_out, int out_size, void* d_ws, size_t ws_size,
                              hipStream_t stream) {
  (void)in_sizes; (void)n_in; (void)out_size; (void)ws_size;
  const float* x    = (const float*)d_in[0];
  const float* wrd  = (const float*)d_in[1];
  const float* wqkv = (const float*)d_in[2];
  const float* dw0  = (const float*)d_in[3];
  const float* pw0  = (const float*)d_in[4];
  const float* dw1  = (const float*)d_in[5];
  const float* pw1  = (const float*)d_in[6];
  const float* dw2  = (const float*)d_in[7];
  const float* pw2  = (const float*)d_in[8];
  const float* wrd2 = (const float*)d_in[9];
  const float* wprj = (const float*)d_in[10];
  const float* bprj = (const float*)d_in[11];
  float* out = (float*)d_out;

  char* p = (char*)d_ws;
  auto nxt = [&](size_t bytes) {
    char* r = p;
    p += (bytes + 255) & ~(size_t)255;
    return (bf16*)r;
  };
  // alias block: xb (8.39M) + xr (4.19M) == qkvT (12.58M); disjoint lifetimes
  bf16* xb   = nxt(8192ull * 512 * 2);
  bf16* xr   = nxt(8192ull * 256 * 2);
  bf16* qkvT = xb;  // [2][768][4096] NCHW, written after xb/xr are dead
  bf16* wrT  = nxt(256ull * 512 * 2);
  bf16* wqT  = nxt(768ull * 256 * 2);
  bf16* wr2T = nxt(768ull * 3072 * 2);
  bf16* wpT  = nxt(512ull * 256 * 2);
  bf16* qkv  = nxt(8192ull * 768 * 2);
  bf16* dtmp = nxt(8192ull * 768 * 2);   // dw output (NCHW)
  bf16* y0   = nxt(8192ull * 768 * 2);
  bf16* y1   = nxt(8192ull * 768 * 2);
  bf16* y2   = nxt(8192ull * 768 * 2);
  bf16* msq  = nxt(8192ull * 768 * 2);
  bf16* pwT  = msq;  // pw output (NCHW) — dead before GEMM3 writes msq
  bf16* ao   = nxt(8192ull * 256 * 2);

  // prep
  k_cvt_bf16<<<(8192 * 512 / 4) / 256, 256, 0, stream>>>(x, xb);
  k_transpose_bf16<<<dim3(512 / 32, 256 / 32), 256, 0, stream>>>(wrd, wrT, 512, 256);
  k_transpose_bf16<<<dim3(256 / 32, 768 / 32), 256, 0, stream>>>(wqkv, wqT, 256, 768);
  k_transpose_bf16<<<dim3(3072 / 32, 768 / 32), 256, 0, stream>>>(wrd2, wr2T, 3072, 768);
  k_transpose_bf16<<<dim3(256 / 32, 512 / 32), 256, 0, stream>>>(wprj, wpT, 256, 512);

  // GEMM1: xr = x @ w_reduce
  k_gemm_bt<<<dim3(64, 2), 256, 0, stream>>>(xb, xb, xb, xb, wrT, xr, nullptr, nullptr,
                                             256, 512, 512, 1 << 20);
  // GEMM2: qkv = xr @ w_qkv
  k_gemm_bt<<<dim3(64, 6), 256, 0, stream>>>(xr, xr, xr, xr, wqT, qkv, nullptr, nullptr,
                                             768, 256, 256, 1 << 20);

  // qkv [2][4096][768] -> qkvT [2][768][4096]
  k_transpose2d<<<dim3(12, 64, 2), 256, 0, stream>>>(qkv, qkvT, 4096, 768);

  // conv branches: dw (NCHW) -> pw (NCHW) -> transpose back to token-major
  k_dwconv_img<3><<<dim3(768, 2), 256, 0, stream>>>(qkvT, dw0, dtmp);
  k_pwconv_img<<<dim3(192, 2, 2), 256, 0, stream>>>(dtmp, pw0, pwT);
  k_transpose2d<<<dim3(64, 12, 2), 256, 0, stream>>>(pwT, y0, 768, 4096);

  k_dwconv_img<5><<<dim3(768, 2), 256, 0, stream>>>(qkvT, dw1, dtmp);
  k_pwconv_img<<<dim3(192, 2, 2), 256, 0, stream>>>(dtmp, pw1, pwT);
  k_transpose2d<<<dim3(64, 12, 2), 256, 0, stream>>>(pwT, y1, 768, 4096);

  k_dwconv_img<7><<<dim3(768, 2), 256, 0, stream>>>(qkvT, dw2, dtmp);
  k_pwconv_img<<<dim3(192, 2, 2), 256, 0, stream>>>(dtmp, pw2, pwT);
  k_transpose2d<<<dim3(64, 12, 2), 256, 0, stream>>>(pwT, y2, 768, 4096);

  // GEMM3: msq = [qkv|y0|y1|y2] @ w_reduce2  (K=3072 via 4 sources)
  k_gemm_bt<<<dim3(64, 6), 256, 0, stream>>>(qkv, y0, y1, y2, wr2T, msq, nullptr, nullptr,
                                             768, 3072, 768, 12);

  // attention
  k_attn<<<dim3(32, 32), 256, 0, stream>>>(msq, ao);

  // GEMM4: out = ao @ w_proj + b_proj
  k_gemm_bt<<<dim3(64, 4), 256, 0, stream>>>(ao, ao, ao, ao, wpT, nullptr, out, bprj,
                                             512, 256, 256, 1 << 20);
}

// Round 4
// 394.890 us; speedup vs baseline: 5.2985x; 1.1372x over previous
//
#include <hip/hip_runtime.h>
#include <hip/hip_bf16.h>

typedef __bf16 bf16x8 __attribute__((ext_vector_type(8)));
typedef __bf16 bf16x4v __attribute__((ext_vector_type(4)));
typedef float f32x4 __attribute__((ext_vector_type(4)));
typedef unsigned int u32x4 __attribute__((ext_vector_type(4)));

using bf16 = __hip_bfloat16;

// ---------------- elementwise fp32 -> bf16 ----------------
__global__ __launch_bounds__(256) void k_cvt_bf16(const float* __restrict__ in,
                                                  bf16* __restrict__ out) {
  const int i = (blockIdx.x * 256 + threadIdx.x) * 4;
  float4 v = *reinterpret_cast<const float4*>(in + i);
  out[i + 0] = __float2bfloat16(v.x);
  out[i + 1] = __float2bfloat16(v.y);
  out[i + 2] = __float2bfloat16(v.z);
  out[i + 3] = __float2bfloat16(v.w);
}

// ---------------- weight transpose + convert: wt[n][k] = (bf16)w[k][n] ----------------
__global__ __launch_bounds__(256) void k_transpose_bf16(const float* __restrict__ w,
                                                        bf16* __restrict__ wt,
                                                        int K, int N) {
  __shared__ float t[32][33];
  const int k0 = blockIdx.x * 32, n0 = blockIdx.y * 32;
  const int tx = threadIdx.x & 31, ty = threadIdx.x >> 5;
#pragma unroll
  for (int i = 0; i < 32; i += 8)
    t[ty + i][tx] = w[(size_t)(k0 + ty + i) * N + n0 + tx];
  __syncthreads();
#pragma unroll
  for (int i = 0; i < 32; i += 8)
    wt[(size_t)(n0 + ty + i) * K + k0 + tx] = __float2bfloat16(t[tx][ty + i]);
}

// ---------------- bf16 2D transpose per batch: in [z][R][C] -> out [z][C][R] ----------------
__global__ __launch_bounds__(256) void k_transpose2d(const bf16* __restrict__ in,
                                                     bf16* __restrict__ out,
                                                     int R, int C) {
  __shared__ unsigned short tl[64][65];
  const int c0 = blockIdx.x * 64, r0 = blockIdx.y * 64;
  const size_t zb = (size_t)blockIdx.z * R * C;
  const int tx = threadIdx.x & 63, ty = threadIdx.x >> 6;
  const unsigned short* ip = (const unsigned short*)in + zb;
  unsigned short* op = (unsigned short*)out + zb;
#pragma unroll
  for (int i = 0; i < 64; i += 4)
    tl[ty + i][tx] = ip[(size_t)(r0 + ty + i) * C + c0 + tx];
  __syncthreads();
#pragma unroll
  for (int i = 0; i < 64; i += 4)
    op[(size_t)(c0 + ty + i) * R + r0 + tx] = tl[tx][ty + i];
}

// ---------------- GEMM: C[M,N] = A[M,K] * Bt[N,K]^T  (bf16 in, fp32 acc) ----------------
// global_load_lds width-16 staging (m97 structure).
__global__ __launch_bounds__(256) void k_gemm_bt(
    const bf16* __restrict__ A0, const bf16* __restrict__ A1,
    const bf16* __restrict__ A2, const bf16* __restrict__ A3,
    const bf16* __restrict__ Bt, bf16* __restrict__ Cb,
    float* __restrict__ Cf, const float* __restrict__ bias,
    int N, int K, int srcK, int split_bk) {
  __shared__ __align__(16) bf16 As[128 * 64];
  __shared__ __align__(16) bf16 Bs[128 * 64];
  const int tid = threadIdx.x;
  const int lane = tid & 63;
  const int wv = tid >> 6;
  const size_t M0 = (size_t)blockIdx.x * 128;
  const int N0 = blockIdx.y * 128;
  const int wr = (wv >> 1) * 64, wc = (wv & 1) * 64;
  const int fr = lane & 15, fo = (lane >> 4) * 8;
  const int lrow = lane >> 3, lcol = (lane & 7) << 3;
  f32x4 acc[4][4] = {};

  const int nsteps = K >> 6;
  for (int kt = 0; kt < nsteps; ++kt) {
    const int s = kt / split_bk;
    const bf16* __restrict__ Ak = (s == 0) ? A0 : (s == 1) ? A1 : (s == 2) ? A2 : A3;
    const size_t aofs = (size_t)(kt - s * split_bk) * 64;
    const size_t bofs = (size_t)kt * 64;
    __syncthreads();
#pragma unroll
    for (int ld = 0; ld < 4; ++ld) {
      const int row = wv * 32 + ld * 8 + lrow;
      const bf16* ga = Ak + (M0 + row) * (size_t)srcK + aofs + lcol;
      __builtin_amdgcn_global_load_lds(
          (const __attribute__((address_space(1))) unsigned int*)ga,
          (__attribute__((address_space(3))) unsigned int*)(As + (wv * 32 + ld * 8) * 64),
          16, 0, 0);
      const bf16* gb = Bt + (size_t)(N0 + row) * K + bofs + lcol;
      __builtin_amdgcn_global_load_lds(
          (const __attribute__((address_space(1))) unsigned int*)gb,
          (__attribute__((address_space(3))) unsigned int*)(Bs + (wv * 32 + ld * 8) * 64),
          16, 0, 0);
    }
    __syncthreads();
#pragma unroll
    for (int kk = 0; kk < 64; kk += 32) {
      bf16x8 a[4], b[4];
#pragma unroll
      for (int m = 0; m < 4; ++m)
        a[m] = *reinterpret_cast<const bf16x8*>(As + (wr + m * 16 + fr) * 64 + kk + fo);
#pragma unroll
      for (int n = 0; n < 4; ++n)
        b[n] = *reinterpret_cast<const bf16x8*>(Bs + (wc + n * 16 + fr) * 64 + kk + fo);
#pragma unroll
      for (int m = 0; m < 4; ++m)
#pragma unroll
        for (int n = 0; n < 4; ++n)
          acc[m][n] = __builtin_amdgcn_mfma_f32_16x16x32_bf16(a[m], b[n], acc[m][n], 0, 0, 0);
    }
  }

  const int rb = (lane >> 4) * 4;
#pragma unroll
  for (int m = 0; m < 4; ++m) {
#pragma unroll
    for (int n = 0; n < 4; ++n) {
      const size_t row = M0 + wr + m * 16 + rb;
      const int col = N0 + wc + n * 16 + fr;
      if (Cb != nullptr) {
#pragma unroll
        for (int r = 0; r < 4; ++r)
          Cb[(row + r) * N + col] = __float2bfloat16(acc[m][n][r]);
      } else {
        const float bb = bias[col];
#pragma unroll
        for (int r = 0; r < 4; ++r)
          Cf[(row + r) * N + col] = acc[m][n][r] + bb;
      }
    }
  }
}

// ---------------- depthwise conv, NCHW planes, LDS-staged ----------------
template <int KS>
__global__ __launch_bounds__(256) void k_dwconv_img(const bf16* __restrict__ in,
                                                    const float* __restrict__ w,
                                                    bf16* __restrict__ out) {
  constexpr int P = KS / 2;
  constexpr int ROWS = 64 + 2 * P;
  constexpr int PITCH = 80;
  constexpr int NCHUNK = ROWS * PITCH * 2 / 16;
  __shared__ __align__(16) bf16 pl[ROWS * PITCH];
  const int t = threadIdx.x;
  const int c = blockIdx.x, b = blockIdx.y;
  const bf16* __restrict__ ip = in + ((size_t)b * 768 + c) * 4096;
  bf16* __restrict__ op = out + ((size_t)b * 768 + c) * 4096;

  u32x4* pl4 = reinterpret_cast<u32x4*>(pl);
  for (int i = t; i < NCHUNK; i += 256) pl4[i] = u32x4{0, 0, 0, 0};
  __syncthreads();
  for (int q = t; q < 512; q += 256) {
    const int px0 = q * 8;
    const int y = px0 >> 6, x = px0 & 63;
    u32x4 v = *reinterpret_cast<const u32x4*>(ip + px0);
    *reinterpret_cast<u32x4*>(&pl[(y + P) * PITCH + 8 + x]) = v;
  }
  __syncthreads();

  float wk[KS * KS];
#pragma unroll
  for (int i = 0; i < KS * KS; ++i) wk[i] = w[c * KS * KS + i];

  const int x = t & 63;
  const int y0 = (t >> 6) * 16;
  float win[KS][KS];
#pragma unroll
  for (int r = 0; r < 2 * P; ++r)
#pragma unroll
    for (int kx = 0; kx < KS; ++kx)
      win[r % KS][kx] = __bfloat162float(pl[(y0 + r) * PITCH + 8 + x - P + kx]);
#pragma unroll
  for (int yy = 0; yy < 16; ++yy) {
    constexpr int twoP = 2 * P;
#pragma unroll
    for (int kx = 0; kx < KS; ++kx)
      win[(yy + twoP) % KS][kx] =
          __bfloat162float(pl[(y0 + yy + twoP) * PITCH + 8 + x - P + kx]);
    float acc = 0.f;
#pragma unroll
    for (int ky = 0; ky < KS; ++ky)
#pragma unroll
      for (int kx = 0; kx < KS; ++kx)
        acc += win[(yy + ky) % KS][kx] * wk[ky * KS + kx];
    op[(y0 + yy) * 64 + x] = __float2bfloat16(acc);
  }
}

// ---------------- grouped 1x1 conv, NCHW planes ----------------
__global__ __launch_bounds__(256) void k_pwconv_img(const bf16* __restrict__ in,
                                                    const float* __restrict__ w,
                                                    bf16* __restrict__ out) {
  const int co0 = blockIdx.x * 4;
  const int g = co0 >> 5;
  const int b = blockIdx.z;
  const int px = blockIdx.y * 2048 + threadIdx.x * 8;
  const bf16* __restrict__ ip = in + ((size_t)b * 768 + g * 32) * 4096 + px;
  float acc[4][8] = {};
#pragma unroll
  for (int ci = 0; ci < 32; ++ci) {
    const bf16x8 v = *reinterpret_cast<const bf16x8*>(ip + (size_t)ci * 4096);
    float fv[8];
#pragma unroll
    for (int j = 0; j < 8; ++j) fv[j] = (float)v[j];
#pragma unroll
    for (int q = 0; q < 4; ++q) {
      const float wq = w[(co0 + q) * 32 + ci];
#pragma unroll
      for (int j = 0; j < 8; ++j) acc[q][j] += wq * fv[j];
    }
  }
#pragma unroll
  for (int q = 0; q < 4; ++q) {
    bf16x8 o;
#pragma unroll
    for (int j = 0; j < 8; ++j) o[j] = (__bf16)acc[q][j];
    *reinterpret_cast<bf16x8*>(out + ((size_t)b * 768 + co0 + q) * 4096 + px) = o;
  }
}

// ---------------- chunked flash attention (swapped-QK^T, QBLK=128) ----------------
// grid: x = q-tile of 128 rows (16), y = combo b*16 + h*2 + chunk (32)
__global__ __launch_bounds__(256) void k_attn(const bf16* __restrict__ msq,
                                              bf16* __restrict__ out) {
  const int qt = blockIdx.x;
  const int combo = blockIdx.y;
  const int b = combo >> 4;
  const int h = (combo >> 1) & 7;
  const int ck = combo & 1;
  const int tid = threadIdx.x, lane = tid & 63, wv = tid >> 6;
  const int fr = lane & 15, hi = lane >> 4, fo = hi * 8;
  const size_t base = (size_t)b * 4096 * 768;
  const int n0 = ck * 2048 + qt * 128;

  __shared__ __align__(16) bf16 Kl[64][40];       // K tile [kv][hd]
  __shared__ __align__(16) bf16 Vt[32][72];       // V^T tile [hd][kv]
  __shared__ __align__(16) bf16 Pl[4][2][16][72]; // per-wave/frag P [q][kv]

  const float scale = 0.17677669529663687f;  // 1/sqrt(32)
  bf16x8 qf[2];
#pragma unroll
  for (int t = 0; t < 2; ++t) {
    const int qrow = n0 + t * 64 + wv * 16 + fr;
    const bf16x8 v =
        *reinterpret_cast<const bf16x8*>(msq + base + (size_t)qrow * 768 + h * 32 + fo);
#pragma unroll
    for (int j = 0; j < 8; ++j) qf[t][j] = (__bf16)((float)v[j] * scale);
  }

  f32x4 oacc[2][2] = {};
  float mrun[2] = {-1e30f, -1e30f};
  float lrun[2] = {0.f, 0.f};
  const int sr = tid >> 2, sdc = (tid & 3) << 3;

  for (int kt = 0; kt < 32; ++kt) {
    const int m0 = ck * 2048 + kt * 64;
    __syncthreads();
    {
      const size_t rbase = base + (size_t)(m0 + sr) * 768 + h * 32;
      u32x4 kv = *reinterpret_cast<const u32x4*>(msq + rbase + 256 + sdc);
      *reinterpret_cast<u32x4*>(&Kl[sr][sdc]) = kv;
      u32x4 vvv = *reinterpret_cast<const u32x4*>(msq + rbase + 512 + sdc);
      const bf16* vp = reinterpret_cast<const bf16*>(&vvv);
#pragma unroll
      for (int j = 0; j < 8; ++j) Vt[sdc + j][sr] = vp[j];
    }
    __syncthreads();

    bf16x8 kf[4];
#pragma unroll
    for (int j = 0; j < 4; ++j)
      kf[j] = *reinterpret_cast<const bf16x8*>(&Kl[j * 16 + fr][fo]);

    // swapped S^T = K Q^T : lane owns q-row fr, holds kv = 16j + 4*hi + r
#pragma unroll
    for (int t = 0; t < 2; ++t) {
      f32x4 sacc[4];
#pragma unroll
      for (int j = 0; j < 4; ++j) {
        const f32x4 z = {0.f, 0.f, 0.f, 0.f};
        sacc[j] = __builtin_amdgcn_mfma_f32_16x16x32_bf16(kf[j], qf[t], z, 0, 0, 0);
      }
      float mx = -1e30f;
#pragma unroll
      for (int j = 0; j < 4; ++j)
#pragma unroll
        for (int r = 0; r < 4; ++r) mx = fmaxf(mx, sacc[j][r]);
      mx = fmaxf(mx, __shfl_xor(mx, 16));
      mx = fmaxf(mx, __shfl_xor(mx, 32));
      const float mnew = fmaxf(mrun[t], mx);
      const float corr = __expf(mrun[t] - mnew);
      mrun[t] = mnew;
      float sm = 0.f;
#pragma unroll
      for (int j = 0; j < 4; ++j) {
        bf16x4v pk;
#pragma unroll
        for (int r = 0; r < 4; ++r) {
          const float pz = __expf(sacc[j][r] - mnew);
          sm += pz;
          pk[r] = (__bf16)pz;
        }
        *reinterpret_cast<bf16x4v*>(&Pl[wv][t][fr][j * 16 + hi * 4]) = pk;
      }
      sm += __shfl_xor(sm, 16);
      sm += __shfl_xor(sm, 32);
      lrun[t] = lrun[t] * corr + sm;
      // broadcast corr to accumulator rows q' = hi*4 + r
#pragma unroll
      for (int r = 0; r < 4; ++r) {
        const float cf = __shfl(corr, hi * 4 + r);
        oacc[t][0][r] *= cf;
        oacc[t][1][r] *= cf;
      }
    }

    // O += P @ V
#pragma unroll
    for (int t = 0; t < 2; ++t)
#pragma unroll
      for (int kk = 0; kk < 2; ++kk) {
        const bf16x8 pa = *reinterpret_cast<const bf16x8*>(&Pl[wv][t][fr][kk * 32 + fo]);
#pragma unroll
        for (int nb = 0; nb < 2; ++nb) {
          const bf16x8 vb = *reinterpret_cast<const bf16x8*>(&Vt[nb * 16 + fr][kk * 32 + fo]);
          oacc[t][nb] = __builtin_amdgcn_mfma_f32_16x16x32_bf16(pa, vb, oacc[t][nb], 0, 0, 0);
        }
      }
  }

#pragma unroll
  for (int t = 0; t < 2; ++t)
#pragma unroll
    for (int r = 0; r < 4; ++r) {
      const float lf = __shfl(lrun[t], hi * 4 + r);
      const float inv = 1.f / lf;
      const int row = n0 + t * 64 + wv * 16 + hi * 4 + r;
#pragma unroll
      for (int nb = 0; nb < 2; ++nb)
        out[((size_t)b * 4096 + row) * 256 + h * 32 + nb * 16 + fr] =
            __float2bfloat16(oacc[t][nb][r] * inv);
    }
}

// ---------------- launcher ----------------
extern "C" void kernel_launch(void* const* d_in, const int* in_sizes, int n_in,
                              void* d_out, int out_size, void* d_ws, size_t ws_size,
                              hipStream_t stream) {
  (void)in_sizes; (void)n_in; (void)out_size; (void)ws_size;
  const float* x    = (const float*)d_in[0];
  const float* wrd  = (const float*)d_in[1];
  const float* wqkv = (const float*)d_in[2];
  const float* dw0  = (const float*)d_in[3];
  const float* pw0  = (const float*)d_in[4];
  const float* dw1  = (const float*)d_in[5];
  const float* pw1  = (const float*)d_in[6];
  const float* dw2  = (const float*)d_in[7];
  const float* pw2  = (const float*)d_in[8];
  const float* wrd2 = (const float*)d_in[9];
  const float* wprj = (const float*)d_in[10];
  const float* bprj = (const float*)d_in[11];
  float* out = (float*)d_out;

  char* p = (char*)d_ws;
  auto nxt = [&](size_t bytes) {
    char* r = p;
    p += (bytes + 255) & ~(size_t)255;
    return (bf16*)r;
  };
  bf16* xb   = nxt(8192ull * 512 * 2);
  bf16* xr   = nxt(8192ull * 256 * 2);
  bf16* qkvT = xb;  // [2][768][4096] NCHW; xb/xr dead by then
  bf16* wrT  = nxt(256ull * 512 * 2);
  bf16* wqT  = nxt(768ull * 256 * 2);
  bf16* wr2T = nxt(768ull * 3072 * 2);
  bf16* wpT  = nxt(512ull * 256 * 2);
  bf16* qkv  = nxt(8192ull * 768 * 2);
  bf16* dtmp = nxt(8192ull * 768 * 2);
  bf16* y0   = nxt(8192ull * 768 * 2);
  bf16* y1   = nxt(8192ull * 768 * 2);
  bf16* y2   = nxt(8192ull * 768 * 2);
  bf16* msq  = nxt(8192ull * 768 * 2);
  bf16* pwT  = msq;  // NCHW pw output; dead before GEMM3 writes msq
  bf16* ao   = nxt(8192ull * 256 * 2);

  // prep
  k_cvt_bf16<<<(8192 * 512 / 4) / 256, 256, 0, stream>>>(x, xb);
  k_transpose_bf16<<<dim3(512 / 32, 256 / 32), 256, 0, stream>>>(wrd, wrT, 512, 256);
  k_transpose_bf16<<<dim3(256 / 32, 768 / 32), 256, 0, stream>>>(wqkv, wqT, 256, 768);
  k_transpose_bf16<<<dim3(3072 / 32, 768 / 32), 256, 0, stream>>>(wrd2, wr2T, 3072, 768);
  k_transpose_bf16<<<dim3(256 / 32, 512 / 32), 256, 0, stream>>>(wprj, wpT, 256, 512);

  // GEMM1: xr = x @ w_reduce
  k_gemm_bt<<<dim3(64, 2), 256, 0, stream>>>(xb, xb, xb, xb, wrT, xr, nullptr, nullptr,
                                             256, 512, 512, 1 << 20);
  // GEMM2: qkv = xr @ w_qkv
  k_gemm_bt<<<dim3(64, 6), 256, 0, stream>>>(xr, xr, xr, xr, wqT, qkv, nullptr, nullptr,
                                             768, 256, 256, 1 << 20);

  // qkv [2][4096][768] -> qkvT [2][768][4096]
  k_transpose2d<<<dim3(12, 64, 2), 256, 0, stream>>>(qkv, qkvT, 4096, 768);

  // conv branches
  k_dwconv_img<3><<<dim3(768, 2), 256, 0, stream>>>(qkvT, dw0, dtmp);
  k_pwconv_img<<<dim3(192, 2, 2), 256, 0, stream>>>(dtmp, pw0, pwT);
  k_transpose2d<<<dim3(64, 12, 2), 256, 0, stream>>>(pwT, y0, 768, 4096);

  k_dwconv_img<5><<<dim3(768, 2), 256, 0, stream>>>(qkvT, dw1, dtmp);
  k_pwconv_img<<<dim3(192, 2, 2), 256, 0, stream>>>(dtmp, pw1, pwT);
  k_transpose2d<<<dim3(64, 12, 2), 256, 0, stream>>>(pwT, y1, 768, 4096);

  k_dwconv_img<7><<<dim3(768, 2), 256, 0, stream>>>(qkvT, dw2, dtmp);
  k_pwconv_img<<<dim3(192, 2, 2), 256, 0, stream>>>(dtmp, pw2, pwT);
  k_transpose2d<<<dim3(64, 12, 2), 256, 0, stream>>>(pwT, y2, 768, 4096);

  // GEMM3: msq = [qkv|y0|y1|y2] @ w_reduce2  (K=3072 via 4 sources)
  k_gemm_bt<<<dim3(64, 6), 256, 0, stream>>>(qkv, y0, y1, y2, wr2T, msq, nullptr, nullptr,
                                             768, 3072, 768, 12);

  // attention (128-row q-tiles)
  k_attn<<<dim3(16, 32), 256, 0, stream>>>(msq, ao);

  // GEMM4: out = ao @ w_proj + b_proj
  k_gemm_bt<<<dim3(64, 4), 256, 0, stream>>>(ao, ao, ao, ao, wpT, nullptr, out, bprj,
                                             512, 256, 256, 1 << 20);
}

// Round 6
// 380.322 us; speedup vs baseline: 5.5014x; 1.0383x over previous
//
#include <hip/hip_runtime.h>
#include <hip/hip_bf16.h>

typedef __bf16 bf16x8 __attribute__((ext_vector_type(8)));
typedef __bf16 bf16x4v __attribute__((ext_vector_type(4)));
typedef float f32x4 __attribute__((ext_vector_type(4)));
typedef unsigned int u32x4 __attribute__((ext_vector_type(4)));

using bf16 = __hip_bfloat16;

// ---------------- elementwise fp32 -> bf16 ----------------
__global__ __launch_bounds__(256) void k_cvt_bf16(const float* __restrict__ in,
                                                  bf16* __restrict__ out) {
  const int i = (blockIdx.x * 256 + threadIdx.x) * 4;
  float4 v = *reinterpret_cast<const float4*>(in + i);
  out[i + 0] = __float2bfloat16(v.x);
  out[i + 1] = __float2bfloat16(v.y);
  out[i + 2] = __float2bfloat16(v.z);
  out[i + 3] = __float2bfloat16(v.w);
}

// ---------------- weight transpose + convert: wt[n][k] = (bf16)w[k][n] ----------------
__global__ __launch_bounds__(256) void k_transpose_bf16(const float* __restrict__ w,
                                                        bf16* __restrict__ wt,
                                                        int K, int N) {
  __shared__ float t[32][33];
  const int k0 = blockIdx.x * 32, n0 = blockIdx.y * 32;
  const int tx = threadIdx.x & 31, ty = threadIdx.x >> 5;
#pragma unroll
  for (int i = 0; i < 32; i += 8)
    t[ty + i][tx] = w[(size_t)(k0 + ty + i) * N + n0 + tx];
  __syncthreads();
#pragma unroll
  for (int i = 0; i < 32; i += 8)
    wt[(size_t)(n0 + ty + i) * K + k0 + tx] = __float2bfloat16(t[tx][ty + i]);
}

// ---------------- bf16 2D transpose per batch: in [z][R][C] -> out [z][C][R] ----------------
__global__ __launch_bounds__(256) void k_transpose2d(const bf16* __restrict__ in,
                                                     bf16* __restrict__ out,
                                                     int R, int C) {
  __shared__ unsigned short tl[64][65];
  const int c0 = blockIdx.x * 64, r0 = blockIdx.y * 64;
  const size_t zb = (size_t)blockIdx.z * R * C;
  const int tx = threadIdx.x & 63, ty = threadIdx.x >> 6;
  const unsigned short* ip = (const unsigned short*)in + zb;
  unsigned short* op = (unsigned short*)out + zb;
#pragma unroll
  for (int i = 0; i < 64; i += 4)
    tl[ty + i][tx] = ip[(size_t)(r0 + ty + i) * C + c0 + tx];
  __syncthreads();
#pragma unroll
  for (int i = 0; i < 64; i += 4)
    op[(size_t)(c0 + ty + i) * R + r0 + tx] = tl[tx][ty + i];
}

// ---------------- GEMM: C[M,N] = A[M,K] * Bt[N,K]^T  (bf16 in, fp32 acc) ----------------
// global_load_lds width-16 staging + 2-phase double-buffer prefetch (T3 minimum recipe):
// stage(kt+1) issued BEFORE compute(kt); single barrier per K-step so the
// vmcnt(0) drain lands after the MFMA phase, not before it.
__global__ __launch_bounds__(256) void k_gemm_bt(
    const bf16* __restrict__ A0, const bf16* __restrict__ A1,
    const bf16* __restrict__ A2, const bf16* __restrict__ A3,
    const bf16* __restrict__ Bt, bf16* __restrict__ Cb,
    float* __restrict__ Cf, const float* __restrict__ bias,
    int N, int K, int srcK, int split_bk) {
  __shared__ __align__(16) bf16 As[2][128 * 64];
  __shared__ __align__(16) bf16 Bs[2][128 * 64];
  const int tid = threadIdx.x;
  const int lane = tid & 63;
  const int wv = tid >> 6;
  const size_t M0 = (size_t)blockIdx.x * 128;
  const int N0 = blockIdx.y * 128;
  const int wr = (wv >> 1) * 64, wc = (wv & 1) * 64;
  const int fr = lane & 15, fo = (lane >> 4) * 8;
  const int lrow = lane >> 3, lcol = (lane & 7) << 3;
  f32x4 acc[4][4] = {};

  auto stage = [&](int kt, int buf) {
    const int s = kt / split_bk;
    const bf16* __restrict__ Ak = (s == 0) ? A0 : (s == 1) ? A1 : (s == 2) ? A2 : A3;
    const size_t aofs = (size_t)(kt - s * split_bk) * 64;
    const size_t bofs = (size_t)kt * 64;
#pragma unroll
    for (int ld = 0; ld < 4; ++ld) {
      const int row = wv * 32 + ld * 8 + lrow;
      const bf16* ga = Ak + (M0 + row) * (size_t)srcK + aofs + lcol;
      __builtin_amdgcn_global_load_lds(
          (const __attribute__((address_space(1))) unsigned int*)ga,
          (__attribute__((address_space(3))) unsigned int*)(As[buf] + (wv * 32 + ld * 8) * 64),
          16, 0, 0);
      const bf16* gb = Bt + (size_t)(N0 + row) * K + bofs + lcol;
      __builtin_amdgcn_global_load_lds(
          (const __attribute__((address_space(1))) unsigned int*)gb,
          (__attribute__((address_space(3))) unsigned int*)(Bs[buf] + (wv * 32 + ld * 8) * 64),
          16, 0, 0);
    }
  };

  const int nsteps = K >> 6;
  stage(0, 0);
  __syncthreads();  // vmcnt(0) drain: tile 0 resident
  int cur = 0;
  for (int kt = 0; kt < nsteps; ++kt) {
    if (kt + 1 < nsteps) stage(kt + 1, cur ^ 1);  // in flight during compute
#pragma unroll
    for (int kk = 0; kk < 64; kk += 32) {
      bf16x8 a[4], b[4];
#pragma unroll
      for (int m = 0; m < 4; ++m)
        a[m] = *reinterpret_cast<const bf16x8*>(As[cur] + (wr + m * 16 + fr) * 64 + kk + fo);
#pragma unroll
      for (int n = 0; n < 4; ++n)
        b[n] = *reinterpret_cast<const bf16x8*>(Bs[cur] + (wc + n * 16 + fr) * 64 + kk + fo);
#pragma unroll
      for (int m = 0; m < 4; ++m)
#pragma unroll
        for (int n = 0; n < 4; ++n)
          acc[m][n] = __builtin_amdgcn_mfma_f32_16x16x32_bf16(a[m], b[n], acc[m][n], 0, 0, 0);
    }
    __syncthreads();  // drains vmcnt (next tile ready) + lgkmcnt (cur reads done)
    cur ^= 1;
  }

  const int rb = (lane >> 4) * 4;
#pragma unroll
  for (int m = 0; m < 4; ++m) {
#pragma unroll
    for (int n = 0; n < 4; ++n) {
      const size_t row = M0 + wr + m * 16 + rb;
      const int col = N0 + wc + n * 16 + fr;
      if (Cb != nullptr) {
#pragma unroll
        for (int r = 0; r < 4; ++r)
          Cb[(row + r) * N + col] = __float2bfloat16(acc[m][n][r]);
      } else {
        const float bb = bias[col];
#pragma unroll
        for (int r = 0; r < 4; ++r)
          Cf[(row + r) * N + col] = acc[m][n][r] + bb;
      }
    }
  }
}

// ---------------- depthwise conv, NCHW planes, LDS-staged ----------------
template <int KS>
__global__ __launch_bounds__(256) void k_dwconv_img(const bf16* __restrict__ in,
                                                    const float* __restrict__ w,
                                                    bf16* __restrict__ out) {
  constexpr int P = KS / 2;
  constexpr int ROWS = 64 + 2 * P;
  constexpr int PITCH = 80;
  constexpr int NCHUNK = ROWS * PITCH * 2 / 16;
  __shared__ __align__(16) bf16 pl[ROWS * PITCH];
  const int t = threadIdx.x;
  const int c = blockIdx.x, b = blockIdx.y;
  const bf16* __restrict__ ip = in + ((size_t)b * 768 + c) * 4096;
  bf16* __restrict__ op = out + ((size_t)b * 768 + c) * 4096;

  u32x4* pl4 = reinterpret_cast<u32x4*>(pl);
  for (int i = t; i < NCHUNK; i += 256) pl4[i] = u32x4{0, 0, 0, 0};
  __syncthreads();
  for (int q = t; q < 512; q += 256) {
    const int px0 = q * 8;
    const int y = px0 >> 6, x = px0 & 63;
    u32x4 v = *reinterpret_cast<const u32x4*>(ip + px0);
    *reinterpret_cast<u32x4*>(&pl[(y + P) * PITCH + 8 + x]) = v;
  }
  __syncthreads();

  float wk[KS * KS];
#pragma unroll
  for (int i = 0; i < KS * KS; ++i) wk[i] = w[c * KS * KS + i];

  const int x = t & 63;
  const int y0 = (t >> 6) * 16;
  float win[KS][KS];
#pragma unroll
  for (int r = 0; r < 2 * P; ++r)
#pragma unroll
    for (int kx = 0; kx < KS; ++kx)
      win[r % KS][kx] = __bfloat162float(pl[(y0 + r) * PITCH + 8 + x - P + kx]);
#pragma unroll
  for (int yy = 0; yy < 16; ++yy) {
    constexpr int twoP = 2 * P;
#pragma unroll
    for (int kx = 0; kx < KS; ++kx)
      win[(yy + twoP) % KS][kx] =
          __bfloat162float(pl[(y0 + yy + twoP) * PITCH + 8 + x - P + kx]);
    float acc = 0.f;
#pragma unroll
    for (int ky = 0; ky < KS; ++ky)
#pragma unroll
      for (int kx = 0; kx < KS; ++kx)
        acc += win[(yy + ky) % KS][kx] * wk[ky * KS + kx];
    op[(y0 + yy) * 64 + x] = __float2bfloat16(acc);
  }
}

// ---------------- grouped 1x1 conv, NCHW planes ----------------
__global__ __launch_bounds__(256) void k_pwconv_img(const bf16* __restrict__ in,
                                                    const float* __restrict__ w,
                                                    bf16* __restrict__ out) {
  const int co0 = blockIdx.x * 4;
  const int g = co0 >> 5;
  const int b = blockIdx.z;
  const int px = blockIdx.y * 2048 + threadIdx.x * 8;
  const bf16* __restrict__ ip = in + ((size_t)b * 768 + g * 32) * 4096 + px;
  float acc[4][8] = {};
#pragma unroll
  for (int ci = 0; ci < 32; ++ci) {
    const bf16x8 v = *reinterpret_cast<const bf16x8*>(ip + (size_t)ci * 4096);
    float fv[8];
#pragma unroll
    for (int j = 0; j < 8; ++j) fv[j] = (float)v[j];
#pragma unroll
    for (int q = 0; q < 4; ++q) {
      const float wq = w[(co0 + q) * 32 + ci];
#pragma unroll
      for (int j = 0; j < 8; ++j) acc[q][j] += wq * fv[j];
    }
  }
#pragma unroll
  for (int q = 0; q < 4; ++q) {
    bf16x8 o;
#pragma unroll
    for (int j = 0; j < 8; ++j) o[j] = (__bf16)acc[q][j];
    *reinterpret_cast<bf16x8*>(out + ((size_t)b * 768 + co0 + q) * 4096 + px) = o;
  }
}

// ---------------- chunked flash attention (swapped-QK^T, QBLK=128) ----------------
__global__ __launch_bounds__(256) void k_attn(const bf16* __restrict__ msq,
                                              bf16* __restrict__ out) {
  const int qt = blockIdx.x;
  const int combo = blockIdx.y;
  const int b = combo >> 4;
  const int h = (combo >> 1) & 7;
  const int ck = combo & 1;
  const int tid = threadIdx.x, lane = tid & 63, wv = tid >> 6;
  const int fr = lane & 15, hi = lane >> 4, fo = hi * 8;
  const size_t base = (size_t)b * 4096 * 768;
  const int n0 = ck * 2048 + qt * 128;

  __shared__ __align__(16) bf16 Kl[64][40];
  __shared__ __align__(16) bf16 Vt[32][72];
  __shared__ __align__(16) bf16 Pl[4][2][16][72];

  const float scale = 0.17677669529663687f;
  bf16x8 qf[2];
#pragma unroll
  for (int t = 0; t < 2; ++t) {
    const int qrow = n0 + t * 64 + wv * 16 + fr;
    const bf16x8 v =
        *reinterpret_cast<const bf16x8*>(msq + base + (size_t)qrow * 768 + h * 32 + fo);
#pragma unroll
    for (int j = 0; j < 8; ++j) qf[t][j] = (__bf16)((float)v[j] * scale);
  }

  f32x4 oacc[2][2] = {};
  float mrun[2] = {-1e30f, -1e30f};
  float lrun[2] = {0.f, 0.f};
  const int sr = tid >> 2, sdc = (tid & 3) << 3;

  for (int kt = 0; kt < 32; ++kt) {
    const int m0 = ck * 2048 + kt * 64;
    __syncthreads();
    {
      const size_t rbase = base + (size_t)(m0 + sr) * 768 + h * 32;
      u32x4 kv = *reinterpret_cast<const u32x4*>(msq + rbase + 256 + sdc);
      *reinterpret_cast<u32x4*>(&Kl[sr][sdc]) = kv;
      u32x4 vvv = *reinterpret_cast<const u32x4*>(msq + rbase + 512 + sdc);
      const bf16* vp = reinterpret_cast<const bf16*>(&vvv);
#pragma unroll
      for (int j = 0; j < 8; ++j) Vt[sdc + j][sr] = vp[j];
    }
    __syncthreads();

    bf16x8 kf[4];
#pragma unroll
    for (int j = 0; j < 4; ++j)
      kf[j] = *reinterpret_cast<const bf16x8*>(&Kl[j * 16 + fr][fo]);

#pragma unroll
    for (int t = 0; t < 2; ++t) {
      f32x4 sacc[4];
#pragma unroll
      for (int j = 0; j < 4; ++j) {
        const f32x4 z = {0.f, 0.f, 0.f, 0.f};
        sacc[j] = __builtin_amdgcn_mfma_f32_16x16x32_bf16(kf[j], qf[t], z, 0, 0, 0);
      }
      float mx = -1e30f;
#pragma unroll
      for (int j = 0; j < 4; ++j)
#pragma unroll
        for (int r = 0; r < 4; ++r) mx = fmaxf(mx, sacc[j][r]);
      mx = fmaxf(mx, __shfl_xor(mx, 16));
      mx = fmaxf(mx, __shfl_xor(mx, 32));
      const float mnew = fmaxf(mrun[t], mx);
      const float corr = __expf(mrun[t] - mnew);
      mrun[t] = mnew;
      float sm = 0.f;
#pragma unroll
      for (int j = 0; j < 4; ++j) {
        bf16x4v pk;
#pragma unroll
        for (int r = 0; r < 4; ++r) {
          const float pz = __expf(sacc[j][r] - mnew);
          sm += pz;
          pk[r] = (__bf16)pz;
        }
        *reinterpret_cast<bf16x4v*>(&Pl[wv][t][fr][j * 16 + hi * 4]) = pk;
      }
      sm += __shfl_xor(sm, 16);
      sm += __shfl_xor(sm, 32);
      lrun[t] = lrun[t] * corr + sm;
#pragma unroll
      for (int r = 0; r < 4; ++r) {
        const float cf = __shfl(corr, hi * 4 + r);
        oacc[t][0][r] *= cf;
        oacc[t][1][r] *= cf;
      }
    }

#pragma unroll
    for (int t = 0; t < 2; ++t)
#pragma unroll
      for (int kk = 0; kk < 2; ++kk) {
        const bf16x8 pa = *reinterpret_cast<const bf16x8*>(&Pl[wv][t][fr][kk * 32 + fo]);
#pragma unroll
        for (int nb = 0; nb < 2; ++nb) {
          const bf16x8 vb = *reinterpret_cast<const bf16x8*>(&Vt[nb * 16 + fr][kk * 32 + fo]);
          oacc[t][nb] = __builtin_amdgcn_mfma_f32_16x16x32_bf16(pa, vb, oacc[t][nb], 0, 0, 0);
        }
      }
  }

#pragma unroll
  for (int t = 0; t < 2; ++t)
#pragma unroll
    for (int r = 0; r < 4; ++r) {
      const float lf = __shfl(lrun[t], hi * 4 + r);
      const float inv = 1.f / lf;
      const int row = n0 + t * 64 + wv * 16 + hi * 4 + r;
#pragma unroll
      for (int nb = 0; nb < 2; ++nb)
        out[((size_t)b * 4096 + row) * 256 + h * 32 + nb * 16 + fr] =
            __float2bfloat16(oacc[t][nb][r] * inv);
    }
}

// ---------------- launcher ----------------
extern "C" void kernel_launch(void* const* d_in, const int* in_sizes, int n_in,
                              void* d_out, int out_size, void* d_ws, size_t ws_size,
                              hipStream_t stream) {
  (void)in_sizes; (void)n_in; (void)out_size; (void)ws_size;
  const float* x    = (const float*)d_in[0];
  const float* wrd  = (const float*)d_in[1];
  const float* wqkv = (const float*)d_in[2];
  const float* dw0  = (const float*)d_in[3];
  const float* pw0  = (const float*)d_in[4];
  const float* dw1  = (const float*)d_in[5];
  const float* pw1  = (const float*)d_in[6];
  const float* dw2  = (const float*)d_in[7];
  const float* pw2  = (const float*)d_in[8];
  const float* wrd2 = (const float*)d_in[9];
  const float* wprj = (const float*)d_in[10];
  const float* bprj = (const float*)d_in[11];
  float* out = (float*)d_out;

  char* p = (char*)d_ws;
  auto nxt = [&](size_t bytes) {
    char* r = p;
    p += (bytes + 255) & ~(size_t)255;
    return (bf16*)r;
  };
  bf16* xb   = nxt(8192ull * 512 * 2);
  bf16* xr   = nxt(8192ull * 256 * 2);
  bf16* qkvT = xb;  // [2][768][4096] NCHW; xb/xr dead by then
  bf16* wrT  = nxt(256ull * 512 * 2);
  bf16* wqT  = nxt(768ull * 256 * 2);
  bf16* wr2T = nxt(768ull * 3072 * 2);
  bf16* wpT  = nxt(512ull * 256 * 2);
  bf16* qkv  = nxt(8192ull * 768 * 2);
  bf16* dtmp = nxt(8192ull * 768 * 2);
  bf16* y0   = nxt(8192ull * 768 * 2);
  bf16* y1   = nxt(8192ull * 768 * 2);
  bf16* y2   = nxt(8192ull * 768 * 2);
  bf16* msq  = nxt(8192ull * 768 * 2);
  bf16* pwT  = msq;  // NCHW pw output; dead before GEMM3 writes msq
  bf16* ao   = nxt(8192ull * 256 * 2);

  // prep
  k_cvt_bf16<<<(8192 * 512 / 4) / 256, 256, 0, stream>>>(x, xb);
  k_transpose_bf16<<<dim3(512 / 32, 256 / 32), 256, 0, stream>>>(wrd, wrT, 512, 256);
  k_transpose_bf16<<<dim3(256 / 32, 768 / 32), 256, 0, stream>>>(wqkv, wqT, 256, 768);
  k_transpose_bf16<<<dim3(3072 / 32, 768 / 32), 256, 0, stream>>>(wrd2, wr2T, 3072, 768);
  k_transpose_bf16<<<dim3(256 / 32, 512 / 32), 256, 0, stream>>>(wprj, wpT, 256, 512);

  // GEMM1: xr = x @ w_reduce
  k_gemm_bt<<<dim3(64, 2), 256, 0, stream>>>(xb, xb, xb, xb, wrT, xr, nullptr, nullptr,
                                             256, 512, 512, 1 << 20);
  // GEMM2: qkv = xr @ w_qkv
  k_gemm_bt<<<dim3(64, 6), 256, 0, stream>>>(xr, xr, xr, xr, wqT, qkv, nullptr, nullptr,
                                             768, 256, 256, 1 << 20);

  // qkv [2][4096][768] -> qkvT [2][768][4096]
  k_transpose2d<<<dim3(12, 64, 2), 256, 0, stream>>>(qkv, qkvT, 4096, 768);

  // conv branches
  k_dwconv_img<3><<<dim3(768, 2), 256, 0, stream>>>(qkvT, dw0, dtmp);
  k_pwconv_img<<<dim3(192, 2, 2), 256, 0, stream>>>(dtmp, pw0, pwT);
  k_transpose2d<<<dim3(64, 12, 2), 256, 0, stream>>>(pwT, y0, 768, 4096);

  k_dwconv_img<5><<<dim3(768, 2), 256, 0, stream>>>(qkvT, dw1, dtmp);
  k_pwconv_img<<<dim3(192, 2, 2), 256, 0, stream>>>(dtmp, pw1, pwT);
  k_transpose2d<<<dim3(64, 12, 2), 256, 0, stream>>>(pwT, y1, 768, 4096);

  k_dwconv_img<7><<<dim3(768, 2), 256, 0, stream>>>(qkvT, dw2, dtmp);
  k_pwconv_img<<<dim3(192, 2, 2), 256, 0, stream>>>(dtmp, pw2, pwT);
  k_transpose2d<<<dim3(64, 12, 2), 256, 0, stream>>>(pwT, y2, 768, 4096);

  // GEMM3: msq = [qkv|y0|y1|y2] @ w_reduce2  (K=3072 via 4 sources)
  k_gemm_bt<<<dim3(64, 6), 256, 0, stream>>>(qkv, y0, y1, y2, wr2T, msq, nullptr, nullptr,
                                             768, 3072, 768, 12);

  // attention (128-row q-tiles)
  k_attn<<<dim3(16, 32), 256, 0, stream>>>(msq, ao);

  // GEMM4: out = ao @ w_proj + b_proj
  k_gemm_bt<<<dim3(64, 4), 256, 0, stream>>>(ao, ao, ao, ao, wpT, nullptr, out, bprj,
                                             512, 256, 256, 1 << 20);
}

// Round 7
// 375.222 us; speedup vs baseline: 5.5762x; 1.0136x over previous
//
#include <hip/hip_runtime.h>
#include <hip/hip_bf16.h>

typedef __bf16 bf16x8 __attribute__((ext_vector_type(8)));
typedef __bf16 bf16x4v __attribute__((ext_vector_type(4)));
typedef float f32x4 __attribute__((ext_vector_type(4)));
typedef unsigned int u32x4 __attribute__((ext_vector_type(4)));

using bf16 = __hip_bfloat16;

// ---------------- elementwise fp32 -> bf16 ----------------
__global__ __launch_bounds__(256) void k_cvt_bf16(const float* __restrict__ in,
                                                  bf16* __restrict__ out) {
  const int i = (blockIdx.x * 256 + threadIdx.x) * 4;
  float4 v = *reinterpret_cast<const float4*>(in + i);
  out[i + 0] = __float2bfloat16(v.x);
  out[i + 1] = __float2bfloat16(v.y);
  out[i + 2] = __float2bfloat16(v.z);
  out[i + 3] = __float2bfloat16(v.w);
}

// ---------------- weight transpose + convert: wt[n][k] = (bf16)w[k][n] ----------------
__global__ __launch_bounds__(256) void k_transpose_bf16(const float* __restrict__ w,
                                                        bf16* __restrict__ wt,
                                                        int K, int N) {
  __shared__ float t[32][33];
  const int k0 = blockIdx.x * 32, n0 = blockIdx.y * 32;
  const int tx = threadIdx.x & 31, ty = threadIdx.x >> 5;
#pragma unroll
  for (int i = 0; i < 32; i += 8)
    t[ty + i][tx] = w[(size_t)(k0 + ty + i) * N + n0 + tx];
  __syncthreads();
#pragma unroll
  for (int i = 0; i < 32; i += 8)
    wt[(size_t)(n0 + ty + i) * K + k0 + tx] = __float2bfloat16(t[tx][ty + i]);
}

// ---------------- bf16 2D transpose per batch: in [z][R][C] -> out [z][C][R] ----------------
__global__ __launch_bounds__(256) void k_transpose2d(const bf16* __restrict__ in,
                                                     bf16* __restrict__ out,
                                                     int R, int C) {
  __shared__ unsigned short tl[64][65];
  const int c0 = blockIdx.x * 64, r0 = blockIdx.y * 64;
  const size_t zb = (size_t)blockIdx.z * R * C;
  const int tx = threadIdx.x & 63, ty = threadIdx.x >> 6;
  const unsigned short* ip = (const unsigned short*)in + zb;
  unsigned short* op = (unsigned short*)out + zb;
#pragma unroll
  for (int i = 0; i < 64; i += 4)
    tl[ty + i][tx] = ip[(size_t)(r0 + ty + i) * C + c0 + tx];
  __syncthreads();
#pragma unroll
  for (int i = 0; i < 64; i += 4)
    op[(size_t)(c0 + ty + i) * R + r0 + tx] = tl[tx][ty + i];
}

// ---------------- GEMM: C[M,N] = A[M,K] * Bt[N,K]^T  (bf16 in, fp32 acc) ----------------
// global_load_lds width-16 staging + 2-phase double-buffer prefetch.
__global__ __launch_bounds__(256) void k_gemm_bt(
    const bf16* __restrict__ A0, const bf16* __restrict__ A1,
    const bf16* __restrict__ A2, const bf16* __restrict__ A3,
    const bf16* __restrict__ Bt, bf16* __restrict__ Cb,
    float* __restrict__ Cf, const float* __restrict__ bias,
    int N, int K, int srcK, int split_bk) {
  __shared__ __align__(16) bf16 As[2][128 * 64];
  __shared__ __align__(16) bf16 Bs[2][128 * 64];
  const int tid = threadIdx.x;
  const int lane = tid & 63;
  const int wv = tid >> 6;
  const size_t M0 = (size_t)blockIdx.x * 128;
  const int N0 = blockIdx.y * 128;
  const int wr = (wv >> 1) * 64, wc = (wv & 1) * 64;
  const int fr = lane & 15, fo = (lane >> 4) * 8;
  const int lrow = lane >> 3, lcol = (lane & 7) << 3;
  f32x4 acc[4][4] = {};

  auto stage = [&](int kt, int buf) {
    const int s = kt / split_bk;
    const bf16* __restrict__ Ak = (s == 0) ? A0 : (s == 1) ? A1 : (s == 2) ? A2 : A3;
    const size_t aofs = (size_t)(kt - s * split_bk) * 64;
    const size_t bofs = (size_t)kt * 64;
#pragma unroll
    for (int ld = 0; ld < 4; ++ld) {
      const int row = wv * 32 + ld * 8 + lrow;
      const bf16* ga = Ak + (M0 + row) * (size_t)srcK + aofs + lcol;
      __builtin_amdgcn_global_load_lds(
          (const __attribute__((address_space(1))) unsigned int*)ga,
          (__attribute__((address_space(3))) unsigned int*)(As[buf] + (wv * 32 + ld * 8) * 64),
          16, 0, 0);
      const bf16* gb = Bt + (size_t)(N0 + row) * K + bofs + lcol;
      __builtin_amdgcn_global_load_lds(
          (const __attribute__((address_space(1))) unsigned int*)gb,
          (__attribute__((address_space(3))) unsigned int*)(Bs[buf] + (wv * 32 + ld * 8) * 64),
          16, 0, 0);
    }
  };

  const int nsteps = K >> 6;
  stage(0, 0);
  __syncthreads();  // vmcnt(0) drain: tile 0 resident
  int cur = 0;
  for (int kt = 0; kt < nsteps; ++kt) {
    if (kt + 1 < nsteps) stage(kt + 1, cur ^ 1);  // in flight during compute
#pragma unroll
    for (int kk = 0; kk < 64; kk += 32) {
      bf16x8 a[4], b[4];
#pragma unroll
      for (int m = 0; m < 4; ++m)
        a[m] = *reinterpret_cast<const bf16x8*>(As[cur] + (wr + m * 16 + fr) * 64 + kk + fo);
#pragma unroll
      for (int n = 0; n < 4; ++n)
        b[n] = *reinterpret_cast<const bf16x8*>(Bs[cur] + (wc + n * 16 + fr) * 64 + kk + fo);
#pragma unroll
      for (int m = 0; m < 4; ++m)
#pragma unroll
        for (int n = 0; n < 4; ++n)
          acc[m][n] = __builtin_amdgcn_mfma_f32_16x16x32_bf16(a[m], b[n], acc[m][n], 0, 0, 0);
    }
    __syncthreads();  // drains vmcnt (next tile ready) + lgkmcnt (cur reads done)
    cur ^= 1;
  }

  const int rb = (lane >> 4) * 4;
#pragma unroll
  for (int m = 0; m < 4; ++m) {
#pragma unroll
    for (int n = 0; n < 4; ++n) {
      const size_t row = M0 + wr + m * 16 + rb;
      const int col = N0 + wc + n * 16 + fr;
      if (Cb != nullptr) {
#pragma unroll
        for (int r = 0; r < 4; ++r)
          Cb[(row + r) * N + col] = __float2bfloat16(acc[m][n][r]);
      } else {
        const float bb = bias[col];
#pragma unroll
        for (int r = 0; r < 4; ++r)
          Cf[(row + r) * N + col] = acc[m][n][r] + bb;
      }
    }
  }
}

// ---------------- depthwise conv, NCHW planes, LDS-staged ----------------
template <int KS>
__global__ __launch_bounds__(256) void k_dwconv_img(const bf16* __restrict__ in,
                                                    const float* __restrict__ w,
                                                    bf16* __restrict__ out) {
  constexpr int P = KS / 2;
  constexpr int ROWS = 64 + 2 * P;
  constexpr int PITCH = 80;
  constexpr int NCHUNK = ROWS * PITCH * 2 / 16;
  __shared__ __align__(16) bf16 pl[ROWS * PITCH];
  const int t = threadIdx.x;
  const int c = blockIdx.x, b = blockIdx.y;
  const bf16* __restrict__ ip = in + ((size_t)b * 768 + c) * 4096;
  bf16* __restrict__ op = out + ((size_t)b * 768 + c) * 4096;

  u32x4* pl4 = reinterpret_cast<u32x4*>(pl);
  for (int i = t; i < NCHUNK; i += 256) pl4[i] = u32x4{0, 0, 0, 0};
  __syncthreads();
  for (int q = t; q < 512; q += 256) {
    const int px0 = q * 8;
    const int y = px0 >> 6, x = px0 & 63;
    u32x4 v = *reinterpret_cast<const u32x4*>(ip + px0);
    *reinterpret_cast<u32x4*>(&pl[(y + P) * PITCH + 8 + x]) = v;
  }
  __syncthreads();

  float wk[KS * KS];
#pragma unroll
  for (int i = 0; i < KS * KS; ++i) wk[i] = w[c * KS * KS + i];

  const int x = t & 63;
  const int y0 = (t >> 6) * 16;
  float win[KS][KS];
#pragma unroll
  for (int r = 0; r < 2 * P; ++r)
#pragma unroll
    for (int kx = 0; kx < KS; ++kx)
      win[r % KS][kx] = __bfloat162float(pl[(y0 + r) * PITCH + 8 + x - P + kx]);
#pragma unroll
  for (int yy = 0; yy < 16; ++yy) {
    constexpr int twoP = 2 * P;
#pragma unroll
    for (int kx = 0; kx < KS; ++kx)
      win[(yy + twoP) % KS][kx] =
          __bfloat162float(pl[(y0 + yy + twoP) * PITCH + 8 + x - P + kx]);
    float acc = 0.f;
#pragma unroll
    for (int ky = 0; ky < KS; ++ky)
#pragma unroll
      for (int kx = 0; kx < KS; ++kx)
        acc += win[(yy + ky) % KS][kx] * wk[ky * KS + kx];
    op[(y0 + yy) * 64 + x] = __float2bfloat16(acc);
  }
}

// ---------------- grouped 1x1 conv, NCHW planes ----------------
__global__ __launch_bounds__(256) void k_pwconv_img(const bf16* __restrict__ in,
                                                    const float* __restrict__ w,
                                                    bf16* __restrict__ out) {
  const int co0 = blockIdx.x * 4;
  const int g = co0 >> 5;
  const int b = blockIdx.z;
  const int px = blockIdx.y * 2048 + threadIdx.x * 8;
  const bf16* __restrict__ ip = in + ((size_t)b * 768 + g * 32) * 4096 + px;
  float acc[4][8] = {};
#pragma unroll
  for (int ci = 0; ci < 32; ++ci) {
    const bf16x8 v = *reinterpret_cast<const bf16x8*>(ip + (size_t)ci * 4096);
    float fv[8];
#pragma unroll
    for (int j = 0; j < 8; ++j) fv[j] = (float)v[j];
#pragma unroll
    for (int q = 0; q < 4; ++q) {
      const float wq = w[(co0 + q) * 32 + ci];
#pragma unroll
      for (int j = 0; j < 8; ++j) acc[q][j] += wq * fv[j];
    }
  }
#pragma unroll
  for (int q = 0; q < 4; ++q) {
    bf16x8 o;
#pragma unroll
    for (int j = 0; j < 8; ++j) o[j] = (__bf16)acc[q][j];
    *reinterpret_cast<bf16x8*>(out + ((size_t)b * 768 + co0 + q) * 4096 + px) = o;
  }
}

// ---------------- chunked flash attention (swapped-QK^T, QBLK=128) ----------------
// Pipelined: reg-prefetch K/V for kt+1 during compute of kt; double-buffered
// K/Vt LDS => ONE barrier per kt (writes go to buf^1 while others read buf).
__global__ __launch_bounds__(256) void k_attn(const bf16* __restrict__ msq,
                                              bf16* __restrict__ out) {
  const int qt = blockIdx.x;
  const int combo = blockIdx.y;
  const int b = combo >> 4;
  const int h = (combo >> 1) & 7;
  const int ck = combo & 1;
  const int tid = threadIdx.x, lane = tid & 63, wv = tid >> 6;
  const int fr = lane & 15, hi = lane >> 4, fo = hi * 8;
  const size_t base = (size_t)b * 4096 * 768;
  const int n0 = ck * 2048 + qt * 128;

  __shared__ __align__(16) bf16 Kl[2][64][40];
  __shared__ __align__(16) bf16 Vt[2][32][72];
  __shared__ __align__(16) bf16 Pl[4][2][16][72];

  const float scale = 0.17677669529663687f;
  bf16x8 qf[2];
#pragma unroll
  for (int t = 0; t < 2; ++t) {
    const int qrow = n0 + t * 64 + wv * 16 + fr;
    const bf16x8 v =
        *reinterpret_cast<const bf16x8*>(msq + base + (size_t)qrow * 768 + h * 32 + fo);
#pragma unroll
    for (int j = 0; j < 8; ++j) qf[t][j] = (__bf16)((float)v[j] * scale);
  }

  f32x4 oacc[2][2] = {};
  float mrun[2] = {-1e30f, -1e30f};
  float lrun[2] = {0.f, 0.f};
  const int sr = tid >> 2, sdc = (tid & 3) << 3;

  u32x4 kr, vr;
  auto gload = [&](int kt) {
    const size_t rbase = base + (size_t)(ck * 2048 + kt * 64 + sr) * 768 + h * 32;
    kr = *reinterpret_cast<const u32x4*>(msq + rbase + 256 + sdc);
    vr = *reinterpret_cast<const u32x4*>(msq + rbase + 512 + sdc);
  };
  auto lwrite = [&](int buf) {
    *reinterpret_cast<u32x4*>(&Kl[buf][sr][sdc]) = kr;
    const bf16* vp = reinterpret_cast<const bf16*>(&vr);
#pragma unroll
    for (int j = 0; j < 8; ++j) Vt[buf][sdc + j][sr] = vp[j];
  };

  gload(0);
  lwrite(0);
  int cur = 0;
  for (int kt = 0; kt < 32; ++kt) {
    __syncthreads();  // buf[cur] fully written (prev iter / prologue)
    if (kt + 1 < 32) gload(kt + 1);  // L2 latency hides under compute below

    bf16x8 kf[4];
#pragma unroll
    for (int j = 0; j < 4; ++j)
      kf[j] = *reinterpret_cast<const bf16x8*>(&Kl[cur][j * 16 + fr][fo]);

#pragma unroll
    for (int t = 0; t < 2; ++t) {
      f32x4 sacc[4];
#pragma unroll
      for (int j = 0; j < 4; ++j) {
        const f32x4 z = {0.f, 0.f, 0.f, 0.f};
        sacc[j] = __builtin_amdgcn_mfma_f32_16x16x32_bf16(kf[j], qf[t], z, 0, 0, 0);
      }
      float mx = -1e30f;
#pragma unroll
      for (int j = 0; j < 4; ++j)
#pragma unroll
        for (int r = 0; r < 4; ++r) mx = fmaxf(mx, sacc[j][r]);
      mx = fmaxf(mx, __shfl_xor(mx, 16));
      mx = fmaxf(mx, __shfl_xor(mx, 32));
      const float mnew = fmaxf(mrun[t], mx);
      const float corr = __expf(mrun[t] - mnew);
      mrun[t] = mnew;
      float sm = 0.f;
#pragma unroll
      for (int j = 0; j < 4; ++j) {
        bf16x4v pk;
#pragma unroll
        for (int r = 0; r < 4; ++r) {
          const float pz = __expf(sacc[j][r] - mnew);
          sm += pz;
          pk[r] = (__bf16)pz;
        }
        *reinterpret_cast<bf16x4v*>(&Pl[wv][t][fr][j * 16 + hi * 4]) = pk;
      }
      sm += __shfl_xor(sm, 16);
      sm += __shfl_xor(sm, 32);
      lrun[t] = lrun[t] * corr + sm;
#pragma unroll
      for (int r = 0; r < 4; ++r) {
        const float cf = __shfl(corr, hi * 4 + r);
        oacc[t][0][r] *= cf;
        oacc[t][1][r] *= cf;
      }
    }

#pragma unroll
    for (int t = 0; t < 2; ++t)
#pragma unroll
      for (int kk = 0; kk < 2; ++kk) {
        const bf16x8 pa = *reinterpret_cast<const bf16x8*>(&Pl[wv][t][fr][kk * 32 + fo]);
#pragma unroll
        for (int nb = 0; nb < 2; ++nb) {
          const bf16x8 vb =
              *reinterpret_cast<const bf16x8*>(&Vt[cur][nb * 16 + fr][kk * 32 + fo]);
          oacc[t][nb] = __builtin_amdgcn_mfma_f32_16x16x32_bf16(pa, vb, oacc[t][nb], 0, 0, 0);
        }
      }

    if (kt + 1 < 32) lwrite(cur ^ 1);  // safe: others read buf[cur] only
    cur ^= 1;
  }

#pragma unroll
  for (int t = 0; t < 2; ++t)
#pragma unroll
    for (int r = 0; r < 4; ++r) {
      const float lf = __shfl(lrun[t], hi * 4 + r);
      const float inv = 1.f / lf;
      const int row = n0 + t * 64 + wv * 16 + hi * 4 + r;
#pragma unroll
      for (int nb = 0; nb < 2; ++nb)
        out[((size_t)b * 4096 + row) * 256 + h * 32 + nb * 16 + fr] =
            __float2bfloat16(oacc[t][nb][r] * inv);
    }
}

// ---------------- launcher ----------------
extern "C" void kernel_launch(void* const* d_in, const int* in_sizes, int n_in,
                              void* d_out, int out_size, void* d_ws, size_t ws_size,
                              hipStream_t stream) {
  (void)in_sizes; (void)n_in; (void)out_size; (void)ws_size;
  const float* x    = (const float*)d_in[0];
  const float* wrd  = (const float*)d_in[1];
  const float* wqkv = (const float*)d_in[2];
  const float* dw0  = (const float*)d_in[3];
  const float* pw0  = (const float*)d_in[4];
  const float* dw1  = (const float*)d_in[5];
  const float* pw1  = (const float*)d_in[6];
  const float* dw2  = (const float*)d_in[7];
  const float* pw2  = (const float*)d_in[8];
  const float* wrd2 = (const float*)d_in[9];
  const float* wprj = (const float*)d_in[10];
  const float* bprj = (const float*)d_in[11];
  float* out = (float*)d_out;

  char* p = (char*)d_ws;
  auto nxt = [&](size_t bytes) {
    char* r = p;
    p += (bytes + 255) & ~(size_t)255;
    return (bf16*)r;
  };
  bf16* xb   = nxt(8192ull * 512 * 2);
  bf16* xr   = nxt(8192ull * 256 * 2);
  bf16* qkvT = xb;  // [2][768][4096] NCHW; xb/xr dead by then
  bf16* wrT  = nxt(256ull * 512 * 2);
  bf16* wqT  = nxt(768ull * 256 * 2);
  bf16* wr2T = nxt(768ull * 3072 * 2);
  bf16* wpT  = nxt(512ull * 256 * 2);
  bf16* qkv  = nxt(8192ull * 768 * 2);
  bf16* dtmp = nxt(8192ull * 768 * 2);
  bf16* y0   = nxt(8192ull * 768 * 2);
  bf16* y1   = nxt(8192ull * 768 * 2);
  bf16* y2   = nxt(8192ull * 768 * 2);
  bf16* msq  = nxt(8192ull * 768 * 2);
  bf16* pwT  = msq;  // NCHW pw output; dead before GEMM3 writes msq
  bf16* ao   = nxt(8192ull * 256 * 2);

  // prep
  k_cvt_bf16<<<(8192 * 512 / 4) / 256, 256, 0, stream>>>(x, xb);
  k_transpose_bf16<<<dim3(512 / 32, 256 / 32), 256, 0, stream>>>(wrd, wrT, 512, 256);
  k_transpose_bf16<<<dim3(256 / 32, 768 / 32), 256, 0, stream>>>(wqkv, wqT, 256, 768);
  k_transpose_bf16<<<dim3(3072 / 32, 768 / 32), 256, 0, stream>>>(wrd2, wr2T, 3072, 768);
  k_transpose_bf16<<<dim3(256 / 32, 512 / 32), 256, 0, stream>>>(wprj, wpT, 256, 512);

  // GEMM1: xr = x @ w_reduce
  k_gemm_bt<<<dim3(64, 2), 256, 0, stream>>>(xb, xb, xb, xb, wrT, xr, nullptr, nullptr,
                                             256, 512, 512, 1 << 20);
  // GEMM2: qkv = xr @ w_qkv
  k_gemm_bt<<<dim3(64, 6), 256, 0, stream>>>(xr, xr, xr, xr, wqT, qkv, nullptr, nullptr,
                                             768, 256, 256, 1 << 20);

  // qkv [2][4096][768] -> qkvT [2][768][4096]
  k_transpose2d<<<dim3(12, 64, 2), 256, 0, stream>>>(qkv, qkvT, 4096, 768);

  // conv branches
  k_dwconv_img<3><<<dim3(768, 2), 256, 0, stream>>>(qkvT, dw0, dtmp);
  k_pwconv_img<<<dim3(192, 2, 2), 256, 0, stream>>>(dtmp, pw0, pwT);
  k_transpose2d<<<dim3(64, 12, 2), 256, 0, stream>>>(pwT, y0, 768, 4096);

  k_dwconv_img<5><<<dim3(768, 2), 256, 0, stream>>>(qkvT, dw1, dtmp);
  k_pwconv_img<<<dim3(192, 2, 2), 256, 0, stream>>>(dtmp, pw1, pwT);
  k_transpose2d<<<dim3(64, 12, 2), 256, 0, stream>>>(pwT, y1, 768, 4096);

  k_dwconv_img<7><<<dim3(768, 2), 256, 0, stream>>>(qkvT, dw2, dtmp);
  k_pwconv_img<<<dim3(192, 2, 2), 256, 0, stream>>>(dtmp, pw2, pwT);
  k_transpose2d<<<dim3(64, 12, 2), 256, 0, stream>>>(pwT, y2, 768, 4096);

  // GEMM3: msq = [qkv|y0|y1|y2] @ w_reduce2  (K=3072 via 4 sources)
  k_gemm_bt<<<dim3(64, 6), 256, 0, stream>>>(qkv, y0, y1, y2, wr2T, msq, nullptr, nullptr,
                                             768, 3072, 768, 12);

  // attention (128-row q-tiles)
  k_attn<<<dim3(16, 32), 256, 0, stream>>>(msq, ao);

  // GEMM4: out = ao @ w_proj + b_proj
  k_gemm_bt<<<dim3(64, 4), 256, 0, stream>>>(ao, ao, ao, ao, wpT, nullptr, out, bprj,
                                             512, 256, 256, 1 << 20);
}

// Round 8
// 373.387 us; speedup vs baseline: 5.6036x; 1.0049x over previous
//
#include <hip/hip_runtime.h>
#include <hip/hip_bf16.h>

typedef __bf16 bf16x8 __attribute__((ext_vector_type(8)));
typedef __bf16 bf16x4v __attribute__((ext_vector_type(4)));
typedef float f32x4 __attribute__((ext_vector_type(4)));
typedef unsigned int u32x4 __attribute__((ext_vector_type(4)));

using bf16 = __hip_bfloat16;

// ---------------- elementwise fp32 -> bf16 ----------------
__global__ __launch_bounds__(256) void k_cvt_bf16(const float* __restrict__ in,
                                                  bf16* __restrict__ out) {
  const int i = (blockIdx.x * 256 + threadIdx.x) * 4;
  float4 v = *reinterpret_cast<const float4*>(in + i);
  out[i + 0] = __float2bfloat16(v.x);
  out[i + 1] = __float2bfloat16(v.y);
  out[i + 2] = __float2bfloat16(v.z);
  out[i + 3] = __float2bfloat16(v.w);
}

// ---------------- weight transpose + convert: wt[n][k] = (bf16)w[k][n] ----------------
// K = output row stride; covers only the (grid.x*32) x (grid.y*32) region.
__global__ __launch_bounds__(256) void k_transpose_bf16(const float* __restrict__ w,
                                                        bf16* __restrict__ wt,
                                                        int K, int N) {
  __shared__ float t[32][33];
  const int k0 = blockIdx.x * 32, n0 = blockIdx.y * 32;
  const int tx = threadIdx.x & 31, ty = threadIdx.x >> 5;
#pragma unroll
  for (int i = 0; i < 32; i += 8)
    t[ty + i][tx] = w[(size_t)(k0 + ty + i) * N + n0 + tx];
  __syncthreads();
#pragma unroll
  for (int i = 0; i < 32; i += 8)
    wt[(size_t)(n0 + ty + i) * K + k0 + tx] = __float2bfloat16(t[tx][ty + i]);
}

// ---------------- fused w12T[n][k] = (bf16) sum_j wrd[k][j]*wqkv[j][n] ----------------
// n<768, k<512, j<256. grid (12, 8); block 256 = 64 n-lanes x 4 k-chunks of 16.
__global__ __launch_bounds__(256) void k_fuse_w12(const float* __restrict__ wrd,
                                                  const float* __restrict__ wqkv,
                                                  bf16* __restrict__ w12T) {
  const int n = blockIdx.x * 64 + (threadIdx.x & 63);
  const int k0 = blockIdx.y * 64 + (threadIdx.x >> 6) * 16;
  float acc[16] = {};
  for (int j = 0; j < 256; ++j) {
    const float wq = wqkv[(size_t)j * 768 + n];
#pragma unroll
    for (int e = 0; e < 16; ++e) acc[e] += wrd[(size_t)(k0 + e) * 256 + j] * wq;
  }
  bf16x8 o0, o1;
#pragma unroll
  for (int e = 0; e < 8; ++e) { o0[e] = (__bf16)acc[e]; o1[e] = (__bf16)acc[8 + e]; }
  *reinterpret_cast<bf16x8*>(w12T + (size_t)n * 512 + k0) = o0;
  *reinterpret_cast<bf16x8*>(w12T + (size_t)n * 512 + k0 + 8) = o1;
}

// ---------------- fold grouped-1x1 pw into wr2T sections ----------------
// wr2T[n][768*(i+1)+c] = sum_q pw_i[(g*32+q)*32 + (c&31)] * w2[(768*(i+1)+g*32+q)*768+n]
// grid (24 g, 12 n-tiles, 3 i); block 256 = 64 n-lanes x 4 c-chunks of 8.
__global__ __launch_bounds__(256) void k_fuse_pw(const float* __restrict__ pw0,
                                                 const float* __restrict__ pw1,
                                                 const float* __restrict__ pw2,
                                                 const float* __restrict__ w2,
                                                 bf16* __restrict__ wr2T) {
  const int g = blockIdx.x;
  const int n0 = blockIdx.y * 64;
  const int i = blockIdx.z;
  const float* __restrict__ pw = (i == 0) ? pw0 : (i == 1) ? pw1 : pw2;
  __shared__ float pwL[32][36];
  {
    const int q = threadIdx.x >> 3, c4 = (threadIdx.x & 7) * 4;
    float4 v = *reinterpret_cast<const float4*>(pw + (size_t)(g * 32 + q) * 32 + c4);
    *reinterpret_cast<float4*>(&pwL[q][c4]) = v;
  }
  __syncthreads();
  const int n = n0 + (threadIdx.x & 63);
  const int ch = threadIdx.x >> 6;
  const int kbase = 768 * (i + 1) + g * 32;
  float acc[8] = {};
  for (int q = 0; q < 32; ++q) {
    const float w2v = w2[(size_t)(kbase + q) * 768 + n];
#pragma unroll
    for (int e = 0; e < 8; ++e) acc[e] += pwL[q][ch * 8 + e] * w2v;
  }
  bf16x8 o;
#pragma unroll
  for (int e = 0; e < 8; ++e) o[e] = (__bf16)acc[e];
  *reinterpret_cast<bf16x8*>(wr2T + (size_t)n * 3072 + kbase + ch * 8) = o;
}

// ---------------- bf16 2D transpose per batch: in [z][R][C] -> out [z][C][R] ----------------
__global__ __launch_bounds__(256) void k_transpose2d(const bf16* __restrict__ in,
                                                     bf16* __restrict__ out,
                                                     int R, int C) {
  __shared__ unsigned short tl[64][65];
  const int c0 = blockIdx.x * 64, r0 = blockIdx.y * 64;
  const size_t zb = (size_t)blockIdx.z * R * C;
  const int tx = threadIdx.x & 63, ty = threadIdx.x >> 6;
  const unsigned short* ip = (const unsigned short*)in + zb;
  unsigned short* op = (unsigned short*)out + zb;
#pragma unroll
  for (int i = 0; i < 64; i += 4)
    tl[ty + i][tx] = ip[(size_t)(r0 + ty + i) * C + c0 + tx];
  __syncthreads();
#pragma unroll
  for (int i = 0; i < 64; i += 4)
    op[(size_t)(c0 + ty + i) * R + r0 + tx] = tl[tx][ty + i];
}

// ---------------- GEMM: C[M,N] = A[M,K] * Bt[N,K]^T  (bf16 in, fp32 acc) ----------------
// global_load_lds width-16 staging + 2-phase double-buffer prefetch.
__global__ __launch_bounds__(256) void k_gemm_bt(
    const bf16* __restrict__ A0, const bf16* __restrict__ A1,
    const bf16* __restrict__ A2, const bf16* __restrict__ A3,
    const bf16* __restrict__ Bt, bf16* __restrict__ Cb,
    float* __restrict__ Cf, const float* __restrict__ bias,
    int N, int K, int srcK, int split_bk) {
  __shared__ __align__(16) bf16 As[2][128 * 64];
  __shared__ __align__(16) bf16 Bs[2][128 * 64];
  const int tid = threadIdx.x;
  const int lane = tid & 63;
  const int wv = tid >> 6;
  const size_t M0 = (size_t)blockIdx.x * 128;
  const int N0 = blockIdx.y * 128;
  const int wr = (wv >> 1) * 64, wc = (wv & 1) * 64;
  const int fr = lane & 15, fo = (lane >> 4) * 8;
  const int lrow = lane >> 3, lcol = (lane & 7) << 3;
  f32x4 acc[4][4] = {};

  auto stage = [&](int kt, int buf) {
    const int s = kt / split_bk;
    const bf16* __restrict__ Ak = (s == 0) ? A0 : (s == 1) ? A1 : (s == 2) ? A2 : A3;
    const size_t aofs = (size_t)(kt - s * split_bk) * 64;
    const size_t bofs = (size_t)kt * 64;
#pragma unroll
    for (int ld = 0; ld < 4; ++ld) {
      const int row = wv * 32 + ld * 8 + lrow;
      const bf16* ga = Ak + (M0 + row) * (size_t)srcK + aofs + lcol;
      __builtin_amdgcn_global_load_lds(
          (const __attribute__((address_space(1))) unsigned int*)ga,
          (__attribute__((address_space(3))) unsigned int*)(As[buf] + (wv * 32 + ld * 8) * 64),
          16, 0, 0);
      const bf16* gb = Bt + (size_t)(N0 + row) * K + bofs + lcol;
      __builtin_amdgcn_global_load_lds(
          (const __attribute__((address_space(1))) unsigned int*)gb,
          (__attribute__((address_space(3))) unsigned int*)(Bs[buf] + (wv * 32 + ld * 8) * 64),
          16, 0, 0);
    }
  };

  const int nsteps = K >> 6;
  stage(0, 0);
  __syncthreads();
  int cur = 0;
  for (int kt = 0; kt < nsteps; ++kt) {
    if (kt + 1 < nsteps) stage(kt + 1, cur ^ 1);
#pragma unroll
    for (int kk = 0; kk < 64; kk += 32) {
      bf16x8 a[4], b[4];
#pragma unroll
      for (int m = 0; m < 4; ++m)
        a[m] = *reinterpret_cast<const bf16x8*>(As[cur] + (wr + m * 16 + fr) * 64 + kk + fo);
#pragma unroll
      for (int n = 0; n < 4; ++n)
        b[n] = *reinterpret_cast<const bf16x8*>(Bs[cur] + (wc + n * 16 + fr) * 64 + kk + fo);
#pragma unroll
      for (int m = 0; m < 4; ++m)
#pragma unroll
        for (int n = 0; n < 4; ++n)
          acc[m][n] = __builtin_amdgcn_mfma_f32_16x16x32_bf16(a[m], b[n], acc[m][n], 0, 0, 0);
    }
    __syncthreads();
    cur ^= 1;
  }

  const int rb = (lane >> 4) * 4;
#pragma unroll
  for (int m = 0; m < 4; ++m) {
#pragma unroll
    for (int n = 0; n < 4; ++n) {
      const size_t row = M0 + wr + m * 16 + rb;
      const int col = N0 + wc + n * 16 + fr;
      if (Cb != nullptr) {
#pragma unroll
        for (int r = 0; r < 4; ++r)
          Cb[(row + r) * N + col] = __float2bfloat16(acc[m][n][r]);
      } else {
        const float bb = bias[col];
#pragma unroll
        for (int r = 0; r < 4; ++r)
          Cf[(row + r) * N + col] = acc[m][n][r] + bb;
      }
    }
  }
}

// ---------------- depthwise conv, NCHW planes, LDS-staged ----------------
template <int KS>
__global__ __launch_bounds__(256) void k_dwconv_img(const bf16* __restrict__ in,
                                                    const float* __restrict__ w,
                                                    bf16* __restrict__ out) {
  constexpr int P = KS / 2;
  constexpr int ROWS = 64 + 2 * P;
  constexpr int PITCH = 80;
  constexpr int NCHUNK = ROWS * PITCH * 2 / 16;
  __shared__ __align__(16) bf16 pl[ROWS * PITCH];
  const int t = threadIdx.x;
  const int c = blockIdx.x, b = blockIdx.y;
  const bf16* __restrict__ ip = in + ((size_t)b * 768 + c) * 4096;
  bf16* __restrict__ op = out + ((size_t)b * 768 + c) * 4096;

  u32x4* pl4 = reinterpret_cast<u32x4*>(pl);
  for (int i = t; i < NCHUNK; i += 256) pl4[i] = u32x4{0, 0, 0, 0};
  __syncthreads();
  for (int q = t; q < 512; q += 256) {
    const int px0 = q * 8;
    const int y = px0 >> 6, x = px0 & 63;
    u32x4 v = *reinterpret_cast<const u32x4*>(ip + px0);
    *reinterpret_cast<u32x4*>(&pl[(y + P) * PITCH + 8 + x]) = v;
  }
  __syncthreads();

  float wk[KS * KS];
#pragma unroll
  for (int i = 0; i < KS * KS; ++i) wk[i] = w[c * KS * KS + i];

  const int x = t & 63;
  const int y0 = (t >> 6) * 16;
  float win[KS][KS];
#pragma unroll
  for (int r = 0; r < 2 * P; ++r)
#pragma unroll
    for (int kx = 0; kx < KS; ++kx)
      win[r % KS][kx] = __bfloat162float(pl[(y0 + r) * PITCH + 8 + x - P + kx]);
#pragma unroll
  for (int yy = 0; yy < 16; ++yy) {
    constexpr int twoP = 2 * P;
#pragma unroll
    for (int kx = 0; kx < KS; ++kx)
      win[(yy + twoP) % KS][kx] =
          __bfloat162float(pl[(y0 + yy + twoP) * PITCH + 8 + x - P + kx]);
    float acc = 0.f;
#pragma unroll
    for (int ky = 0; ky < KS; ++ky)
#pragma unroll
      for (int kx = 0; kx < KS; ++kx)
        acc += win[(yy + ky) % KS][kx] * wk[ky * KS + kx];
    op[(y0 + yy) * 64 + x] = __float2bfloat16(acc);
  }
}

// ---------------- chunked flash attention (swapped-QK^T, QBLK=64) ----------------
// 1-barrier pipelined dbuf; Vt col-XOR-swizzle (conflict-free scatter writes);
// defer-max (THR=8, init m=0). grid (32 q-tiles, 32 combos).
__global__ __launch_bounds__(256) void k_attn(const bf16* __restrict__ msq,
                                              bf16* __restrict__ out) {
  const int qt = blockIdx.x;
  const int combo = blockIdx.y;
  const int b = combo >> 4;
  const int h = (combo >> 1) & 7;
  const int ck = combo & 1;
  const int tid = threadIdx.x, lane = tid & 63, wv = tid >> 6;
  const int fr = lane & 15, hi = lane >> 4, fo = hi * 8;
  const size_t base = (size_t)b * 4096 * 768;
  const int n0 = ck * 2048 + qt * 64;

  __shared__ __align__(16) bf16 Kl[2][64][40];  // K tile [kv][hd]
  __shared__ __align__(16) bf16 Vt[2][32][72];  // V^T [d][kv ^ swz(d)]
  __shared__ __align__(16) bf16 Pl[4][16][72];  // per-wave P [q][kv]

  const float scale = 0.17677669529663687f;  // 1/sqrt(32)
  bf16x8 qf;
  {
    const int qrow = n0 + wv * 16 + fr;
    const bf16x8 v =
        *reinterpret_cast<const bf16x8*>(msq + base + (size_t)qrow * 768 + h * 32 + fo);
#pragma unroll
    for (int j = 0; j < 8; ++j) qf[j] = (__bf16)((float)v[j] * scale);
  }

  f32x4 oacc[2] = {};
  float mrun = 0.f, lrun = 0.f;
  const int sr = tid >> 2, sdc = (tid & 3) << 3;
  const int vswz = (tid & 3) << 4;  // = ((d>>3)&3)<<4 for d = sdc..sdc+7

  u32x4 kr, vr;
  auto gload = [&](int kt) {
    const size_t rbase = base + (size_t)(ck * 2048 + kt * 64 + sr) * 768 + h * 32;
    kr = *reinterpret_cast<const u32x4*>(msq + rbase + 256 + sdc);
    vr = *reinterpret_cast<const u32x4*>(msq + rbase + 512 + sdc);
  };
  auto lwrite = [&](int buf) {
    *reinterpret_cast<u32x4*>(&Kl[buf][sr][sdc]) = kr;
    const bf16* vp = reinterpret_cast<const bf16*>(&vr);
#pragma unroll
    for (int j = 0; j < 8; ++j) Vt[buf][sdc + j][sr ^ vswz] = vp[j];
  };

  gload(0);
  lwrite(0);
  int cur = 0;
  for (int kt = 0; kt < 32; ++kt) {
    __syncthreads();  // buf[cur] fully written
    if (kt + 1 < 32) gload(kt + 1);

    // swapped S^T = K Q^T: lane owns q-row fr, kv = 16j + 4*hi + r in-lane
    f32x4 sacc[4];
#pragma unroll
    for (int j = 0; j < 4; ++j) {
      const bf16x8 kf = *reinterpret_cast<const bf16x8*>(&Kl[cur][j * 16 + fr][fo]);
      const f32x4 z = {0.f, 0.f, 0.f, 0.f};
      sacc[j] = __builtin_amdgcn_mfma_f32_16x16x32_bf16(kf, qf, z, 0, 0, 0);
    }
    float mx = -1e30f;
#pragma unroll
    for (int j = 0; j < 4; ++j)
#pragma unroll
      for (int r = 0; r < 4; ++r) mx = fmaxf(mx, sacc[j][r]);
    mx = fmaxf(mx, __shfl_xor(mx, 16));
    mx = fmaxf(mx, __shfl_xor(mx, 32));
    if (!__all(mx <= mrun + 8.f)) {  // rare rescale path
      const float mnew = fmaxf(mrun, mx);
      const float corr = __expf(mrun - mnew);
      mrun = mnew;
      lrun *= corr;
#pragma unroll
      for (int r = 0; r < 4; ++r) {
        const float cf = __shfl(corr, hi * 4 + r);
        oacc[0][r] *= cf;
        oacc[1][r] *= cf;
      }
    }
    float sm = 0.f;
#pragma unroll
    for (int j = 0; j < 4; ++j) {
      bf16x4v pk;
#pragma unroll
      for (int r = 0; r < 4; ++r) {
        const float pz = __expf(sacc[j][r] - mrun);
        sm += pz;
        pk[r] = (__bf16)pz;
      }
      *reinterpret_cast<bf16x4v*>(&Pl[wv][fr][j * 16 + hi * 4]) = pk;
    }
    sm += __shfl_xor(sm, 16);
    sm += __shfl_xor(sm, 32);
    lrun += sm;

    // O += P @ V  (V read with matching col swizzle)
#pragma unroll
    for (int kk = 0; kk < 2; ++kk) {
      const bf16x8 pa = *reinterpret_cast<const bf16x8*>(&Pl[wv][fr][kk * 32 + fo]);
#pragma unroll
      for (int nb = 0; nb < 2; ++nb) {
        const int d = nb * 16 + fr;
        const int colb = (kk * 32 + fo) ^ (((d >> 3) & 3) << 4);
        const bf16x8 vb = *reinterpret_cast<const bf16x8*>(&Vt[cur][d][colb]);
        oacc[nb] = __builtin_amdgcn_mfma_f32_16x16x32_bf16(pa, vb, oacc[nb], 0, 0, 0);
      }
    }

    if (kt + 1 < 32) lwrite(cur ^ 1);
    cur ^= 1;
  }

#pragma unroll
  for (int r = 0; r < 4; ++r) {
    const float lf = __shfl(lrun, hi * 4 + r);
    const float inv = 1.f / lf;
    const int row = n0 + wv * 16 + hi * 4 + r;
#pragma unroll
    for (int nb = 0; nb < 2; ++nb)
      out[((size_t)b * 4096 + row) * 256 + h * 32 + nb * 16 + fr] =
          __float2bfloat16(oacc[nb][r] * inv);
  }
}

// ---------------- launcher ----------------
extern "C" void kernel_launch(void* const* d_in, const int* in_sizes, int n_in,
                              void* d_out, int out_size, void* d_ws, size_t ws_size,
                              hipStream_t stream) {
  (void)in_sizes; (void)n_in; (void)out_size; (void)ws_size;
  const float* x    = (const float*)d_in[0];
  const float* wrd  = (const float*)d_in[1];
  const float* wqkv = (const float*)d_in[2];
  const float* dw0  = (const float*)d_in[3];
  const float* pw0  = (const float*)d_in[4];
  const float* dw1  = (const float*)d_in[5];
  const float* pw1  = (const float*)d_in[6];
  const float* dw2  = (const float*)d_in[7];
  const float* pw2  = (const float*)d_in[8];
  const float* wrd2 = (const float*)d_in[9];
  const float* wprj = (const float*)d_in[10];
  const float* bprj = (const float*)d_in[11];
  float* out = (float*)d_out;

  char* p = (char*)d_ws;
  auto nxt = [&](size_t bytes) {
    char* r = p;
    p += (bytes + 255) & ~(size_t)255;
    return (bf16*)r;
  };
  bf16* xb   = nxt(8192ull * 512 * 2);
  bf16* w12T = nxt(768ull * 512 * 2);
  bf16* wr2T = nxt(768ull * 3072 * 2);
  bf16* wpT  = nxt(512ull * 256 * 2);
  bf16* qkv  = nxt(8192ull * 768 * 2);
  bf16* dtmp = nxt(8192ull * 768 * 2);
  bf16* y0   = nxt(8192ull * 768 * 2);
  bf16* y1   = nxt(8192ull * 768 * 2);
  bf16* y2   = nxt(8192ull * 768 * 2);
  bf16* msq  = nxt(8192ull * 768 * 2);
  bf16* qkvT = msq;  // NCHW qkv; dead before GEMM3 writes msq
  bf16* ao   = nxt(8192ull * 256 * 2);

  // prep: convert x; fused weights; transposed weights
  k_cvt_bf16<<<(8192 * 512 / 4) / 256, 256, 0, stream>>>(x, xb);
  k_fuse_w12<<<dim3(12, 8), 256, 0, stream>>>(wrd, wqkv, w12T);
  // wr2T k<768 (qkv section) via transpose; k in [768,3072) via pw-folding
  k_transpose_bf16<<<dim3(24, 24), 256, 0, stream>>>(wrd2, wr2T, 3072, 768);
  k_fuse_pw<<<dim3(24, 12, 3), 256, 0, stream>>>(pw0, pw1, pw2, wrd2, wr2T);
  k_transpose_bf16<<<dim3(256 / 32, 512 / 32), 256, 0, stream>>>(wprj, wpT, 256, 512);

  // fused GEMM1+2: qkv = x @ (w_reduce @ w_qkv)   (M=8192 N=768 K=512)
  k_gemm_bt<<<dim3(64, 6), 256, 0, stream>>>(xb, xb, xb, xb, w12T, qkv, nullptr, nullptr,
                                             768, 512, 512, 1 << 20);

  // qkv [2][4096][768] -> qkvT [2][768][4096]
  k_transpose2d<<<dim3(12, 64, 2), 256, 0, stream>>>(qkv, qkvT, 4096, 768);

  // conv branches: dw (NCHW) -> transpose to token-major (pw folded into GEMM3)
  k_dwconv_img<3><<<dim3(768, 2), 256, 0, stream>>>(qkvT, dw0, dtmp);
  k_transpose2d<<<dim3(64, 12, 2), 256, 0, stream>>>(dtmp, y0, 768, 4096);
  k_dwconv_img<5><<<dim3(768, 2), 256, 0, stream>>>(qkvT, dw1, dtmp);
  k_transpose2d<<<dim3(64, 12, 2), 256, 0, stream>>>(dtmp, y1, 768, 4096);
  k_dwconv_img<7><<<dim3(768, 2), 256, 0, stream>>>(qkvT, dw2, dtmp);
  k_transpose2d<<<dim3(64, 12, 2), 256, 0, stream>>>(dtmp, y2, 768, 4096);

  // GEMM3: msq = [qkv|d0|d1|d2] @ wr2T_fused  (K=3072 via 4 sources)
  k_gemm_bt<<<dim3(64, 6), 256, 0, stream>>>(qkv, y0, y1, y2, wr2T, msq, nullptr, nullptr,
                                             768, 3072, 768, 12);

  // attention (64-row q-tiles, 4 blocks/CU)
  k_attn<<<dim3(32, 32), 256, 0, stream>>>(msq, ao);

  // GEMM4: out = ao @ w_proj + b_proj
  k_gemm_bt<<<dim3(64, 4), 256, 0, stream>>>(ao, ao, ao, ao, wpT, nullptr, out, bprj,
                                             512, 256, 256, 1 << 20);
}

// Round 10
// 322.976 us; speedup vs baseline: 6.4782x; 1.1561x over previous
//
#include <hip/hip_runtime.h>
#include <hip/hip_bf16.h>

typedef __bf16 bf16x8 __attribute__((ext_vector_type(8)));
typedef __bf16 bf16x4v __attribute__((ext_vector_type(4)));
typedef float f32x4 __attribute__((ext_vector_type(4)));
typedef unsigned int u32x4 __attribute__((ext_vector_type(4)));

using bf16 = __hip_bfloat16;

// ---------------- elementwise fp32 -> bf16 ----------------
__global__ __launch_bounds__(256) void k_cvt_bf16(const float* __restrict__ in,
                                                  bf16* __restrict__ out) {
  const int i = (blockIdx.x * 256 + threadIdx.x) * 4;
  float4 v = *reinterpret_cast<const float4*>(in + i);
  out[i + 0] = __float2bfloat16(v.x);
  out[i + 1] = __float2bfloat16(v.y);
  out[i + 2] = __float2bfloat16(v.z);
  out[i + 3] = __float2bfloat16(v.w);
}

// ---------------- weight transpose + convert: wt[n][k] = (bf16)w[k][n] ----------------
// K = output row stride; covers only the (grid.x*32) x (grid.y*32) region.
__global__ __launch_bounds__(256) void k_transpose_bf16(const float* __restrict__ w,
                                                        bf16* __restrict__ wt,
                                                        int K, int N) {
  __shared__ float t[32][33];
  const int k0 = blockIdx.x * 32, n0 = blockIdx.y * 32;
  const int tx = threadIdx.x & 31, ty = threadIdx.x >> 5;
#pragma unroll
  for (int i = 0; i < 32; i += 8)
    t[ty + i][tx] = w[(size_t)(k0 + ty + i) * N + n0 + tx];
  __syncthreads();
#pragma unroll
  for (int i = 0; i < 32; i += 8)
    wt[(size_t)(n0 + ty + i) * K + k0 + tx] = __float2bfloat16(t[tx][ty + i]);
}

// ---------------- fold grouped-1x1 pw into wr2T sections ----------------
__global__ __launch_bounds__(256) void k_fuse_pw(const float* __restrict__ pw0,
                                                 const float* __restrict__ pw1,
                                                 const float* __restrict__ pw2,
                                                 const float* __restrict__ w2,
                                                 bf16* __restrict__ wr2T) {
  const int g = blockIdx.x;
  const int n0 = blockIdx.y * 64;
  const int i = blockIdx.z;
  const float* __restrict__ pw = (i == 0) ? pw0 : (i == 1) ? pw1 : pw2;
  __shared__ float pwL[32][36];
  {
    const int q = threadIdx.x >> 3, c4 = (threadIdx.x & 7) * 4;
    float4 v = *reinterpret_cast<const float4*>(pw + (size_t)(g * 32 + q) * 32 + c4);
    *reinterpret_cast<float4*>(&pwL[q][c4]) = v;
  }
  __syncthreads();
  const int n = n0 + (threadIdx.x & 63);
  const int ch = threadIdx.x >> 6;
  const int kbase = 768 * (i + 1) + g * 32;
  float acc[8] = {};
  for (int q = 0; q < 32; ++q) {
    const float w2v = w2[(size_t)(kbase + q) * 768 + n];
#pragma unroll
    for (int e = 0; e < 8; ++e) acc[e] += pwL[q][ch * 8 + e] * w2v;
  }
  bf16x8 o;
#pragma unroll
  for (int e = 0; e < 8; ++e) o[e] = (__bf16)acc[e];
  *reinterpret_cast<bf16x8*>(wr2T + (size_t)n * 3072 + kbase + ch * 8) = o;
}

// ---------------- bf16 2D transpose per batch: in [z][R][C] -> out [z][C][R] ----------------
__global__ __launch_bounds__(256) void k_transpose2d(const bf16* __restrict__ in,
                                                     bf16* __restrict__ out,
                                                     int R, int C) {
  __shared__ unsigned short tl[64][65];
  const int c0 = blockIdx.x * 64, r0 = blockIdx.y * 64;
  const size_t zb = (size_t)blockIdx.z * R * C;
  const int tx = threadIdx.x & 63, ty = threadIdx.x >> 6;
  const unsigned short* ip = (const unsigned short*)in + zb;
  unsigned short* op = (unsigned short*)out + zb;
#pragma unroll
  for (int i = 0; i < 64; i += 4)
    tl[ty + i][tx] = ip[(size_t)(r0 + ty + i) * C + c0 + tx];
  __syncthreads();
#pragma unroll
  for (int i = 0; i < 64; i += 4)
    op[(size_t)(c0 + ty + i) * R + r0 + tx] = tl[tx][ty + i];
}

// ---------------- GEMM: C[M,N] = A[M,K] * Bt[N,K]^T  (bf16 in, fp32 acc) ----------------
// Tile BM x 128, BK=64; global_load_lds width-16 staging + 2-phase dbuf prefetch.
// 4 waves in 2x2; per-wave tile (BM/2) x 64.
template <int BM>
__global__ __launch_bounds__(256) void k_gemm_bt(
    const bf16* __restrict__ A0, const bf16* __restrict__ A1,
    const bf16* __restrict__ A2, const bf16* __restrict__ A3,
    const bf16* __restrict__ Bt, bf16* __restrict__ Cb,
    float* __restrict__ Cf, const float* __restrict__ bias,
    int N, int K, int srcK, int split_bk) {
  constexpr int MR = BM / 32;  // acc rows per wave
  __shared__ __align__(16) bf16 As[2][BM * 64];
  __shared__ __align__(16) bf16 Bs[2][128 * 64];
  const int tid = threadIdx.x;
  const int lane = tid & 63;
  const int wv = tid >> 6;
  const size_t M0 = (size_t)blockIdx.x * BM;
  const int N0 = blockIdx.y * 128;
  const int wr = (wv >> 1) * (BM / 2), wc = (wv & 1) * 64;
  const int fr = lane & 15, fo = (lane >> 4) * 8;
  const int lrow = lane >> 3, lcol = (lane & 7) << 3;
  f32x4 acc[MR][4] = {};

  auto stage = [&](int kt, int buf) {
    const int s = kt / split_bk;
    const bf16* __restrict__ Ak = (s == 0) ? A0 : (s == 1) ? A1 : (s == 2) ? A2 : A3;
    const size_t aofs = (size_t)(kt - s * split_bk) * 64;
    const size_t bofs = (size_t)kt * 64;
#pragma unroll
    for (int ld = 0; ld < BM / 32; ++ld) {
      const int row = wv * (BM / 4) + ld * 8;
      const bf16* ga = Ak + (M0 + row + lrow) * (size_t)srcK + aofs + lcol;
      __builtin_amdgcn_global_load_lds(
          (const __attribute__((address_space(1))) unsigned int*)ga,
          (__attribute__((address_space(3))) unsigned int*)(As[buf] + row * 64),
          16, 0, 0);
    }
#pragma unroll
    for (int ld = 0; ld < 4; ++ld) {
      const int row = wv * 32 + ld * 8;
      const bf16* gb = Bt + (size_t)(N0 + row + lrow) * K + bofs + lcol;
      __builtin_amdgcn_global_load_lds(
          (const __attribute__((address_space(1))) unsigned int*)gb,
          (__attribute__((address_space(3))) unsigned int*)(Bs[buf] + row * 64),
          16, 0, 0);
    }
  };

  const int nsteps = K >> 6;
  stage(0, 0);
  __syncthreads();
  int cur = 0;
  for (int kt = 0; kt < nsteps; ++kt) {
    if (kt + 1 < nsteps) stage(kt + 1, cur ^ 1);
#pragma unroll
    for (int kk = 0; kk < 64; kk += 32) {
      bf16x8 a[MR], b[4];
#pragma unroll
      for (int m = 0; m < MR; ++m)
        a[m] = *reinterpret_cast<const bf16x8*>(As[cur] + (wr + m * 16 + fr) * 64 + kk + fo);
#pragma unroll
      for (int n = 0; n < 4; ++n)
        b[n] = *reinterpret_cast<const bf16x8*>(Bs[cur] + (wc + n * 16 + fr) * 64 + kk + fo);
#pragma unroll
      for (int m = 0; m < MR; ++m)
#pragma unroll
        for (int n = 0; n < 4; ++n)
          acc[m][n] = __builtin_amdgcn_mfma_f32_16x16x32_bf16(a[m], b[n], acc[m][n], 0, 0, 0);
    }
    __syncthreads();
    cur ^= 1;
  }

  const int rb = (lane >> 4) * 4;
#pragma unroll
  for (int m = 0; m < MR; ++m) {
#pragma unroll
    for (int n = 0; n < 4; ++n) {
      const size_t row = M0 + wr + m * 16 + rb;
      const int col = N0 + wc + n * 16 + fr;
      if (Cb != nullptr) {
#pragma unroll
        for (int r = 0; r < 4; ++r)
          Cb[(row + r) * N + col] = __float2bfloat16(acc[m][n][r]);
      } else {
        const float bb = bias[col];
#pragma unroll
        for (int r = 0; r < 4; ++r)
          Cf[(row + r) * N + col] = acc[m][n][r] + bb;
      }
    }
  }
}

// ---------------- depthwise conv, NCHW planes, LDS-staged ----------------
template <int KS>
__global__ __launch_bounds__(256) void k_dwconv_img(const bf16* __restrict__ in,
                                                    const float* __restrict__ w,
                                                    bf16* __restrict__ out) {
  constexpr int P = KS / 2;
  constexpr int ROWS = 64 + 2 * P;
  constexpr int PITCH = 80;
  constexpr int NCHUNK = ROWS * PITCH * 2 / 16;
  __shared__ __align__(16) bf16 pl[ROWS * PITCH];
  const int t = threadIdx.x;
  const int c = blockIdx.x, b = blockIdx.y;
  const bf16* __restrict__ ip = in + ((size_t)b * 768 + c) * 4096;
  bf16* __restrict__ op = out + ((size_t)b * 768 + c) * 4096;

  u32x4* pl4 = reinterpret_cast<u32x4*>(pl);
  for (int i = t; i < NCHUNK; i += 256) pl4[i] = u32x4{0, 0, 0, 0};
  __syncthreads();
  for (int q = t; q < 512; q += 256) {
    const int px0 = q * 8;
    const int y = px0 >> 6, x = px0 & 63;
    u32x4 v = *reinterpret_cast<const u32x4*>(ip + px0);
    *reinterpret_cast<u32x4*>(&pl[(y + P) * PITCH + 8 + x]) = v;
  }
  __syncthreads();

  float wk[KS * KS];
#pragma unroll
  for (int i = 0; i < KS * KS; ++i) wk[i] = w[c * KS * KS + i];

  const int x = t & 63;
  const int y0 = (t >> 6) * 16;
  float win[KS][KS];
#pragma unroll
  for (int r = 0; r < 2 * P; ++r)
#pragma unroll
    for (int kx = 0; kx < KS; ++kx)
      win[r % KS][kx] = __bfloat162float(pl[(y0 + r) * PITCH + 8 + x - P + kx]);
#pragma unroll
  for (int yy = 0; yy < 16; ++yy) {
    constexpr int twoP = 2 * P;
#pragma unroll
    for (int kx = 0; kx < KS; ++kx)
      win[(yy + twoP) % KS][kx] =
          __bfloat162float(pl[(y0 + yy + twoP) * PITCH + 8 + x - P + kx]);
    float acc = 0.f;
#pragma unroll
    for (int ky = 0; ky < KS; ++ky)
#pragma unroll
      for (int kx = 0; kx < KS; ++kx)
        acc += win[(yy + ky) % KS][kx] * wk[ky * KS + kx];
    op[(y0 + yy) * 64 + x] = __float2bfloat16(acc);
  }
}

// ---------------- chunked flash attention (swapped-QK^T, QBLK=64) ----------------
__global__ __launch_bounds__(256) void k_attn(const bf16* __restrict__ msq,
                                              bf16* __restrict__ out) {
  const int qt = blockIdx.x;
  const int combo = blockIdx.y;
  const int b = combo >> 4;
  const int h = (combo >> 1) & 7;
  const int ck = combo & 1;
  const int tid = threadIdx.x, lane = tid & 63, wv = tid >> 6;
  const int fr = lane & 15, hi = lane >> 4, fo = hi * 8;
  const size_t base = (size_t)b * 4096 * 768;
  const int n0 = ck * 2048 + qt * 64;

  __shared__ __align__(16) bf16 Kl[2][64][40];
  __shared__ __align__(16) bf16 Vt[2][32][72];
  __shared__ __align__(16) bf16 Pl[4][16][72];

  const float scale = 0.17677669529663687f;
  bf16x8 qf;
  {
    const int qrow = n0 + wv * 16 + fr;
    const bf16x8 v =
        *reinterpret_cast<const bf16x8*>(msq + base + (size_t)qrow * 768 + h * 32 + fo);
#pragma unroll
    for (int j = 0; j < 8; ++j) qf[j] = (__bf16)((float)v[j] * scale);
  }

  f32x4 oacc[2] = {};
  float mrun = 0.f, lrun = 0.f;
  const int sr = tid >> 2, sdc = (tid & 3) << 3;
  const int vswz = (tid & 3) << 4;

  u32x4 kr, vr;
  auto gload = [&](int kt) {
    const size_t rbase = base + (size_t)(ck * 2048 + kt * 64 + sr) * 768 + h * 32;
    kr = *reinterpret_cast<const u32x4*>(msq + rbase + 256 + sdc);
    vr = *reinterpret_cast<const u32x4*>(msq + rbase + 512 + sdc);
  };
  auto lwrite = [&](int buf) {
    *reinterpret_cast<u32x4*>(&Kl[buf][sr][sdc]) = kr;
    const bf16* vp = reinterpret_cast<const bf16*>(&vr);
#pragma unroll
    for (int j = 0; j < 8; ++j) Vt[buf][sdc + j][sr ^ vswz] = vp[j];
  };

  gload(0);
  lwrite(0);
  int cur = 0;
  for (int kt = 0; kt < 32; ++kt) {
    __syncthreads();
    if (kt + 1 < 32) gload(kt + 1);

    f32x4 sacc[4];
#pragma unroll
    for (int j = 0; j < 4; ++j) {
      const bf16x8 kf = *reinterpret_cast<const bf16x8*>(&Kl[cur][j * 16 + fr][fo]);
      const f32x4 z = {0.f, 0.f, 0.f, 0.f};
      sacc[j] = __builtin_amdgcn_mfma_f32_16x16x32_bf16(kf, qf, z, 0, 0, 0);
    }
    float mx = -1e30f;
#pragma unroll
    for (int j = 0; j < 4; ++j)
#pragma unroll
      for (int r = 0; r < 4; ++r) mx = fmaxf(mx, sacc[j][r]);
    mx = fmaxf(mx, __shfl_xor(mx, 16));
    mx = fmaxf(mx, __shfl_xor(mx, 32));
    if (!__all(mx <= mrun + 8.f)) {
      const float mnew = fmaxf(mrun, mx);
      const float corr = __expf(mrun - mnew);
      mrun = mnew;
      lrun *= corr;
#pragma unroll
      for (int r = 0; r < 4; ++r) {
        const float cf = __shfl(corr, hi * 4 + r);
        oacc[0][r] *= cf;
        oacc[1][r] *= cf;
      }
    }
    float sm = 0.f;
#pragma unroll
    for (int j = 0; j < 4; ++j) {
      bf16x4v pk;
#pragma unroll
      for (int r = 0; r < 4; ++r) {
        const float pz = __expf(sacc[j][r] - mrun);
        sm += pz;
        pk[r] = (__bf16)pz;
      }
      *reinterpret_cast<bf16x4v*>(&Pl[wv][fr][j * 16 + hi * 4]) = pk;
    }
    sm += __shfl_xor(sm, 16);
    sm += __shfl_xor(sm, 32);
    lrun += sm;

#pragma unroll
    for (int kk = 0; kk < 2; ++kk) {
      const bf16x8 pa = *reinterpret_cast<const bf16x8*>(&Pl[wv][fr][kk * 32 + fo]);
#pragma unroll
      for (int nb = 0; nb < 2; ++nb) {
        const int d = nb * 16 + fr;
        const int colb = (kk * 32 + fo) ^ (((d >> 3) & 3) << 4);
        const bf16x8 vb = *reinterpret_cast<const bf16x8*>(&Vt[cur][d][colb]);
        oacc[nb] = __builtin_amdgcn_mfma_f32_16x16x32_bf16(pa, vb, oacc[nb], 0, 0, 0);
      }
    }

    if (kt + 1 < 32) lwrite(cur ^ 1);
    cur ^= 1;
  }

#pragma unroll
  for (int r = 0; r < 4; ++r) {
    const float lf = __shfl(lrun, hi * 4 + r);
    const float inv = 1.f / lf;
    const int row = n0 + wv * 16 + hi * 4 + r;
#pragma unroll
    for (int nb = 0; nb < 2; ++nb)
      out[((size_t)b * 4096 + row) * 256 + h * 32 + nb * 16 + fr] =
          __float2bfloat16(oacc[nb][r] * inv);
  }
}

// ---------------- launcher ----------------
extern "C" void kernel_launch(void* const* d_in, const int* in_sizes, int n_in,
                              void* d_out, int out_size, void* d_ws, size_t ws_size,
                              hipStream_t stream) {
  (void)in_sizes; (void)n_in; (void)out_size; (void)ws_size;
  const float* x    = (const float*)d_in[0];
  const float* wrd  = (const float*)d_in[1];
  const float* wqkv = (const float*)d_in[2];
  const float* dw0  = (const float*)d_in[3];
  const float* pw0  = (const float*)d_in[4];
  const float* dw1  = (const float*)d_in[5];
  const float* pw1  = (const float*)d_in[6];
  const float* dw2  = (const float*)d_in[7];
  const float* pw2  = (const float*)d_in[8];
  const float* wrd2 = (const float*)d_in[9];
  const float* wprj = (const float*)d_in[10];
  const float* bprj = (const float*)d_in[11];
  float* out = (float*)d_out;

  char* p = (char*)d_ws;
  auto nxt = [&](size_t bytes) {
    char* r = p;
    p += (bytes + 255) & ~(size_t)255;
    return (bf16*)r;
  };
  bf16* xb   = nxt(8192ull * 512 * 2);
  bf16* w12T = nxt(768ull * 512 * 2);
  bf16* wrdB = nxt(512ull * 256 * 2);   // wrd as bf16 (= Bt for w12 fuse-GEMM)
  bf16* wqT  = nxt(768ull * 256 * 2);   // wqkv^T bf16 (= A for w12 fuse-GEMM)
  bf16* wr2T = nxt(768ull * 3072 * 2);
  bf16* wpT  = nxt(512ull * 256 * 2);
  bf16* qkv  = nxt(8192ull * 768 * 2);
  bf16* dtmp = nxt(8192ull * 768 * 2);
  bf16* y0   = nxt(8192ull * 768 * 2);
  bf16* y1   = nxt(8192ull * 768 * 2);
  bf16* y2   = nxt(8192ull * 768 * 2);
  bf16* msq  = nxt(8192ull * 768 * 2);
  bf16* qkvT = msq;  // NCHW qkv; dead before GEMM3 writes msq
  bf16* ao   = nxt(8192ull * 256 * 2);

  // prep: convert x; build fused weights via MFMA GEMM; transposed weights
  k_cvt_bf16<<<(8192 * 512 / 4) / 256, 256, 0, stream>>>(x, xb);
  k_cvt_bf16<<<(512 * 256 / 4) / 256, 256, 0, stream>>>(wrd, wrdB);
  k_transpose_bf16<<<dim3(8, 24), 256, 0, stream>>>(wqkv, wqT, 256, 768);
  // w12T[768][512] = wqT[768][256] @ wrdB[512][256]^T
  k_gemm_bt<64><<<dim3(12, 4), 256, 0, stream>>>(wqT, wqT, wqT, wqT, wrdB, w12T,
                                                 nullptr, nullptr, 512, 256, 256, 1 << 20);
  k_transpose_bf16<<<dim3(24, 24), 256, 0, stream>>>(wrd2, wr2T, 3072, 768);
  k_fuse_pw<<<dim3(24, 12, 3), 256, 0, stream>>>(pw0, pw1, pw2, wrd2, wr2T);
  k_transpose_bf16<<<dim3(256 / 32, 512 / 32), 256, 0, stream>>>(wprj, wpT, 256, 512);

  // fused GEMM1+2: qkv = x @ w12   (M=8192 N=768 K=512)
  k_gemm_bt<64><<<dim3(128, 6), 256, 0, stream>>>(xb, xb, xb, xb, w12T, qkv, nullptr,
                                                  nullptr, 768, 512, 512, 1 << 20);

  // qkv [2][4096][768] -> qkvT [2][768][4096]
  k_transpose2d<<<dim3(12, 64, 2), 256, 0, stream>>>(qkv, qkvT, 4096, 768);

  // conv branches: dw (NCHW) -> transpose to token-major (pw folded into GEMM3)
  k_dwconv_img<3><<<dim3(768, 2), 256, 0, stream>>>(qkvT, dw0, dtmp);
  k_transpose2d<<<dim3(64, 12, 2), 256, 0, stream>>>(dtmp, y0, 768, 4096);
  k_dwconv_img<5><<<dim3(768, 2), 256, 0, stream>>>(qkvT, dw1, dtmp);
  k_transpose2d<<<dim3(64, 12, 2), 256, 0, stream>>>(dtmp, y1, 768, 4096);
  k_dwconv_img<7><<<dim3(768, 2), 256, 0, stream>>>(qkvT, dw2, dtmp);
  k_transpose2d<<<dim3(64, 12, 2), 256, 0, stream>>>(dtmp, y2, 768, 4096);

  // GEMM3: msq = [qkv|d0|d1|d2] @ wr2T_fused  (K=3072 via 4 sources)
  k_gemm_bt<64><<<dim3(128, 6), 256, 0, stream>>>(qkv, y0, y1, y2, wr2T, msq, nullptr,
                                                  nullptr, 768, 3072, 768, 12);

  // attention (64-row q-tiles, 4 blocks/CU)
  k_attn<<<dim3(32, 32), 256, 0, stream>>>(msq, ao);

  // GEMM4: out = ao @ w_proj + b_proj
  k_gemm_bt<64><<<dim3(128, 4), 256, 0, stream>>>(ao, ao, ao, ao, wpT, nullptr, out, bprj,
                                                  512, 256, 256, 1 << 20);
}